// Round 1
// baseline (2794.740 us; speedup 1.0000x reference)
//
#include <hip/hip_runtime.h>
#include <math.h>

// Problem constants (from reference)
constexpr int NN   = 20000;   // nodes
constexpr int EE   = 320000;  // edges
constexpr int CD   = 256;     // channels
constexpr int IND  = 128;     // input features
constexpr int OUTD = 128;     // output features
constexpr int LL   = 3;       // gated blocks
constexpr int GG   = 16;      // graphs
constexpr float EPSV = 1e-5f;

// ---------------------------------------------------------------------------
// CSR build
// ---------------------------------------------------------------------------
__global__ void hist_edges_kernel(const int* __restrict__ dst, int* __restrict__ counts) {
    int e = blockIdx.x * blockDim.x + threadIdx.x;
    if (e < EE) atomicAdd(&counts[dst[e]], 1);
}

__global__ void hist_batch_kernel(const int* __restrict__ batch, int* __restrict__ cntg) {
    int i = blockIdx.x * blockDim.x + threadIdx.x;
    if (i < NN) atomicAdd(&cntg[batch[i]], 1);
}

__global__ __launch_bounds__(1024) void scan_kernel(const int* __restrict__ counts,
                                                    int* __restrict__ offsets,
                                                    float* __restrict__ dinv) {
    __shared__ int ls[1024];
    int t = threadIdx.x;
    const int CHK = (NN + 1023) / 1024;
    int begin = t * CHK;
    int end   = begin + CHK; if (end > NN) end = NN;
    int s = 0;
    for (int i = begin; i < end && i < NN; ++i) s += counts[i];
    ls[t] = s;
    __syncthreads();
    for (int off = 1; off < 1024; off <<= 1) {
        int v = (t >= off) ? ls[t - off] : 0;
        __syncthreads();
        ls[t] += v;
        __syncthreads();
    }
    int run = ls[t] - s;  // exclusive prefix
    for (int i = begin; i < end && i < NN; ++i) {
        offsets[i] = run;
        int c = counts[i];
        run += c;
        dinv[i] = rsqrtf((float)(c + 1));  // deg includes self-loop
    }
    if (t == 1023) offsets[NN] = run;
}

__global__ void fill_kernel(const int* __restrict__ src, const int* __restrict__ dst,
                            const int* __restrict__ offsets, int* __restrict__ cursor,
                            const float* __restrict__ dinv,
                            int* __restrict__ srcs, float* __restrict__ wts) {
    int e = blockIdx.x * blockDim.x + threadIdx.x;
    if (e >= EE) return;
    int d = dst[e];
    int p = atomicAdd(&cursor[d], 1);
    int pos = offsets[d] + p;
    int s = src[e];
    srcs[pos] = s;
    wts[pos]  = dinv[s];
}

// ---------------------------------------------------------------------------
// Tiled f32 GEMM: C[M,N] = A[M,K] * B (+bias).  BT: B stored [N,K] (use B^T)
// ---------------------------------------------------------------------------
template<bool BT, bool BIAS>
__global__ __launch_bounds__(256) void gemm_f32(const float* __restrict__ A,
                                                const float* __restrict__ B,
                                                const float* __restrict__ bias,
                                                float* __restrict__ Cm,
                                                int M, int N, int K) {
    constexpr int BM = 128, BN = 64, BK = 16;
    __shared__ float As[BK][BM];
    __shared__ float Bs[BK][BN];
    const int tid = threadIdx.x;
    const int bm = blockIdx.x * BM;
    const int bn = blockIdx.y * BN;
    const int tm = tid >> 4;   // 0..15
    const int tn = tid & 15;   // 0..15

    float acc[8][4];
    #pragma unroll
    for (int i = 0; i < 8; ++i)
        #pragma unroll
        for (int j = 0; j < 4; ++j) acc[i][j] = 0.f;

    for (int k0 = 0; k0 < K; k0 += BK) {
        // A tile: 128 rows x 16 k, 2 float4/thread, stored transposed
        #pragma unroll
        for (int u = 0; u < 2; ++u) {
            int id  = tid * 2 + u;
            int row = id >> 2;
            int kv  = (id & 3) * 4;
            float4 av = make_float4(0.f, 0.f, 0.f, 0.f);
            int grow = bm + row;
            if (grow < M) av = *(const float4*)&A[(size_t)grow * K + k0 + kv];
            As[kv + 0][row] = av.x;
            As[kv + 1][row] = av.y;
            As[kv + 2][row] = av.z;
            As[kv + 3][row] = av.w;
        }
        // B tile: 16 k x 64 n
        if (BT) {
            int nrow = tid >> 2;          // 0..63
            int kv   = (tid & 3) * 4;     // 0..12
            float4 bv = *(const float4*)&B[(size_t)(bn + nrow) * K + k0 + kv];
            Bs[kv + 0][nrow] = bv.x;
            Bs[kv + 1][nrow] = bv.y;
            Bs[kv + 2][nrow] = bv.z;
            Bs[kv + 3][nrow] = bv.w;
        } else {
            int krow = tid >> 4;          // 0..15
            int nv   = (tid & 15) * 4;    // 0..60
            float4 bv = *(const float4*)&B[(size_t)(k0 + krow) * N + bn + nv];
            *(float4*)&Bs[krow][nv] = bv;
        }
        __syncthreads();

        #pragma unroll
        for (int kk = 0; kk < BK; ++kk) {
            float4 a0 = *(const float4*)&As[kk][tm * 8];
            float4 a1 = *(const float4*)&As[kk][tm * 8 + 4];
            float4 b0 = *(const float4*)&Bs[kk][tn * 4];
            float ar[8] = {a0.x, a0.y, a0.z, a0.w, a1.x, a1.y, a1.z, a1.w};
            float br[4] = {b0.x, b0.y, b0.z, b0.w};
            #pragma unroll
            for (int i = 0; i < 8; ++i)
                #pragma unroll
                for (int j = 0; j < 4; ++j) acc[i][j] += ar[i] * br[j];
        }
        __syncthreads();
    }

    float4 bvec = make_float4(0.f, 0.f, 0.f, 0.f);
    if (BIAS) bvec = *(const float4*)&bias[bn + tn * 4];
    #pragma unroll
    for (int i = 0; i < 8; ++i) {
        int grow = bm + tm * 8 + i;
        if (grow < M) {
            float4 o;
            o.x = acc[i][0] + bvec.x;
            o.y = acc[i][1] + bvec.y;
            o.z = acc[i][2] + bvec.z;
            o.w = acc[i][3] + bvec.w;
            *(float4*)&Cm[(size_t)grow * N + bn + tn * 4] = o;
        }
    }
}

// ---------------------------------------------------------------------------
// Edge aggregation (CSR per-node, one block per node, 256 ch threads)
// ---------------------------------------------------------------------------
__global__ __launch_bounds__(256) void gcn_agg_kernel(const float* __restrict__ m,
                                                      const int* __restrict__ offsets,
                                                      const int* __restrict__ srcs,
                                                      const float* __restrict__ wts,
                                                      const float* __restrict__ dinv,
                                                      const float* __restrict__ bias,
                                                      float* __restrict__ outp) {
    int v = blockIdx.x;
    int c = threadIdx.x;
    float dv = dinv[v];
    int o0 = offsets[v], o1 = offsets[v + 1];
    float acc = 0.f;
    for (int o = o0; o < o1; ++o) {
        int s = srcs[o];
        float w = wts[o];
        acc += w * m[(size_t)s * CD + c];
    }
    outp[(size_t)v * CD + c] = dv * acc + dv * dv * m[(size_t)v * CD + c] + bias[c];
}

__global__ __launch_bounds__(256) void agg_plain_kernel(const float* __restrict__ m,
                                                        const int* __restrict__ offsets,
                                                        const int* __restrict__ srcs,
                                                        float* __restrict__ outp) {
    int v = blockIdx.x;
    int c = threadIdx.x;
    int o0 = offsets[v], o1 = offsets[v + 1];
    float acc = 0.f;
    for (int o = o0; o < o1; ++o) {
        int s = srcs[o];
        acc += m[(size_t)s * CD + c];
    }
    outp[(size_t)v * CD + c] = acc;
}

// ---------------------------------------------------------------------------
// GraphNorm
// ---------------------------------------------------------------------------
__global__ __launch_bounds__(256) void gn_partial_kernel(const float* __restrict__ x,
                                                         const int* __restrict__ batch,
                                                         float* __restrict__ sums,
                                                         float* __restrict__ sumsq) {
    int c = threadIdx.x;
    int node0 = blockIdx.x * 64;
    if (node0 >= NN) return;
    int node1 = node0 + 64; if (node1 > NN) node1 = NN;
    int gcur = batch[node0];
    float s = 0.f, q = 0.f;
    for (int v = node0; v < node1; ++v) {
        int gb = batch[v];
        if (gb != gcur) {
            atomicAdd(&sums[gcur * CD + c], s);
            atomicAdd(&sumsq[gcur * CD + c], q);
            s = 0.f; q = 0.f; gcur = gb;
        }
        float val = x[(size_t)v * CD + c];
        s += val; q += val * val;
    }
    atomicAdd(&sums[gcur * CD + c], s);
    atomicAdd(&sumsq[gcur * CD + c], q);
}

// gelu(exact) + partial sums; writes u into um
__global__ __launch_bounds__(256) void gelu_gn_partial_kernel(const float* __restrict__ x,
                                                              const int* __restrict__ batch,
                                                              float* __restrict__ um,
                                                              float* __restrict__ sums,
                                                              float* __restrict__ sumsq) {
    int c = threadIdx.x;
    int node0 = blockIdx.x * 64;
    if (node0 >= NN) return;
    int node1 = node0 + 64; if (node1 > NN) node1 = NN;
    int gcur = batch[node0];
    float s = 0.f, q = 0.f;
    for (int v = node0; v < node1; ++v) {
        int gb = batch[v];
        if (gb != gcur) {
            atomicAdd(&sums[gcur * CD + c], s);
            atomicAdd(&sumsq[gcur * CD + c], q);
            s = 0.f; q = 0.f; gcur = gb;
        }
        float xv = x[(size_t)v * CD + c];
        float val = 0.5f * xv * (1.f + erff(xv * 0.70710678118654752f));
        um[(size_t)v * CD + c] = val;
        s += val; q += val * val;
    }
    atomicAdd(&sums[gcur * CD + c], s);
    atomicAdd(&sumsq[gcur * CD + c], q);
}

__global__ void gn_finalize_kernel(const float* __restrict__ sums,
                                   const float* __restrict__ sumsq,
                                   const int* __restrict__ cntg,
                                   const float* __restrict__ w,
                                   const float* __restrict__ ms,
                                   float* __restrict__ scaleA,
                                   float* __restrict__ shiftB) {
    int i = blockIdx.x * blockDim.x + threadIdx.x;
    if (i >= GG * CD) return;
    int g = i / CD, c = i % CD;
    float cnt  = fmaxf((float)cntg[g], 1.0f);
    float mean = sums[i] / cnt;
    float ex2  = sumsq[i] / cnt;
    float msm  = ms[c] * mean;
    float var  = ex2 - 2.f * msm * mean + msm * msm;  // E[(x - ms*mean)^2]
    scaleA[i] = w[c] * rsqrtf(var + EPSV);
    shiftB[i] = msm;
}

// apply norm; writes h and g_state.  RES: h += normed (residual), else h = normed
template<bool RES>
__global__ void gn_apply_kernel(const float* __restrict__ x,
                                const int* __restrict__ batch,
                                const float* __restrict__ scaleA,
                                const float* __restrict__ shiftB,
                                const float* __restrict__ bvec,
                                float* __restrict__ h,
                                float* __restrict__ g_state) {
    int i = blockIdx.x * blockDim.x + threadIdx.x;
    if (i >= NN * CD) return;
    int v = i / CD, c = i % CD;
    int gb = batch[v];
    float val = (x[i] - shiftB[gb * CD + c]) * scaleA[gb * CD + c] + bvec[c];
    if (RES) val += h[i];
    h[i] = val;
    g_state[i] = val;
}

// ---------------------------------------------------------------------------
// GRU elementwise
// ---------------------------------------------------------------------------
__global__ void gru_kernel(const float* __restrict__ gi, const float* __restrict__ gh,
                           float* __restrict__ g_state, int rows, int r0) {
    int i = blockIdx.x * blockDim.x + threadIdx.x;
    if (i >= rows * CD) return;
    int rr = i / CD, c = i % CD;
    const float* gip = gi + (size_t)rr * 3 * CD;
    const float* ghp = gh + (size_t)rr * 3 * CD;
    float ir = gip[c], iz = gip[CD + c], in_ = gip[2 * CD + c];
    float hr = ghp[c], hz = ghp[CD + c], hn  = ghp[2 * CD + c];
    float r = 1.f / (1.f + expf(-(ir + hr)));
    float z = 1.f / (1.f + expf(-(iz + hz)));
    float nn = tanhf(in_ + r * hn);
    size_t gidx = (size_t)(r0 + rr) * CD + c;
    float hold = g_state[gidx];
    g_state[gidx] = (1.f - z) * nn + z * hold;
}

// ---------------------------------------------------------------------------
// Host
// ---------------------------------------------------------------------------
extern "C" void kernel_launch(void* const* d_in, const int* in_sizes, int n_in,
                              void* d_out, int out_size, void* d_ws, size_t ws_size,
                              hipStream_t stream) {
    const float* x      = (const float*)d_in[0];
    const int*   ei     = (const int*)d_in[1];
    const int*   batch  = (const int*)d_in[2];
    const float* gcn_w  = (const float*)d_in[3];
    const float* gcn_b  = (const float*)d_in[4];
    const float* gn0_w  = (const float*)d_in[5];
    const float* gn0_b  = (const float*)d_in[6];
    const float* gn0_ms = (const float*)d_in[7];
    const float* ggc_w  = (const float*)d_in[8];
    const float* gru_wih = (const float*)d_in[9];
    const float* gru_whh = (const float*)d_in[10];
    const float* gru_bih = (const float*)d_in[11];
    const float* gru_bhh = (const float*)d_in[12];
    const float* gn_w   = (const float*)d_in[13];
    const float* gn_b   = (const float*)d_in[14];
    const float* gn_ms  = (const float*)d_in[15];
    const float* lin_w  = (const float*)d_in[16];
    const float* lin_b  = (const float*)d_in[17];
    float* outp = (float*)d_out;

    const int* srcv = ei;
    const int* dstv = ei + EE;

    char* base = (char*)d_ws;
    size_t off = 0;
    auto alloc = [&](size_t bytes) -> void* {
        void* p = base + off;
        off = (off + bytes + 255) & ~(size_t)255;
        return p;
    };

    int*   counts  = (int*)alloc(NN * 4);
    int*   cursor  = (int*)alloc(NN * 4);
    int*   cntg    = (int*)alloc(GG * 4);
    size_t zero_end = off;                 // memset [counts, zero_end)
    int*   offsets = (int*)alloc((NN + 1) * 4);
    int*   srcs    = (int*)alloc((size_t)EE * 4);
    float* wts     = (float*)alloc((size_t)EE * 4);
    float* dinv    = (float*)alloc(NN * 4);
    float* sums    = (float*)alloc(GG * CD * 4);
    float* sumsq   = (float*)alloc(GG * CD * 4);
    float* scaleA  = (float*)alloc(GG * CD * 4);
    float* shiftB  = (float*)alloc(GG * CD * 4);
    float* h       = (float*)alloc((size_t)NN * CD * 4);
    float* g       = (float*)alloc((size_t)NN * CD * 4);
    float* m       = (float*)alloc((size_t)NN * CD * 4);
    float* abuf    = (float*)alloc((size_t)NN * CD * 4);

    // chunk size for gi/gh gate buffers, sized to remaining workspace
    size_t rem = (ws_size > off) ? (ws_size - off - 512) : 0;
    size_t per_row = (size_t)2 * 3 * CD * 4;  // gi + gh per row
    int CH = (int)(rem / per_row);
    if (CH > NN) CH = NN;
    if (CH < 256) CH = 256;  // floor; assume ws is at least ~86MB+1.5MB
    float* gi = (float*)alloc((size_t)CH * 3 * CD * 4);
    float* gh = (float*)alloc((size_t)CH * 3 * CD * 4);

    // ---- CSR build + per-graph counts ----
    hipMemsetAsync(counts, 0, zero_end, stream);
    hist_edges_kernel<<<(EE + 255) / 256, 256, 0, stream>>>(dstv, counts);
    hist_batch_kernel<<<(NN + 255) / 256, 256, 0, stream>>>(batch, cntg);
    scan_kernel<<<1, 1024, 0, stream>>>(counts, offsets, dinv);
    fill_kernel<<<(EE + 255) / 256, 256, 0, stream>>>(srcv, dstv, offsets, cursor, dinv, srcs, wts);

    const int gmx = (NN + 127) / 128;  // 157
    const int nb_gn = (NN + 63) / 64;  // 313
    const int nthr_nc = (NN * CD + 255) / 256;

    // ---- GCNConv ----
    gemm_f32<true, false><<<dim3(gmx, CD / 64), 256, 0, stream>>>(x, gcn_w, nullptr, m, NN, CD, IND);
    gcn_agg_kernel<<<NN, 256, 0, stream>>>(m, offsets, srcs, wts, dinv, gcn_b, abuf);

    hipMemsetAsync(sums, 0, 2 * GG * CD * 4, stream);
    gn_partial_kernel<<<nb_gn, 256, 0, stream>>>(abuf, batch, sums, sumsq);
    gn_finalize_kernel<<<(GG * CD + 255) / 256, 256, 0, stream>>>(sums, sumsq, cntg, gn0_w, gn0_ms, scaleA, shiftB);
    gn_apply_kernel<false><<<nthr_nc, 256, 0, stream>>>(abuf, batch, scaleA, shiftB, gn0_b, h, g);

    // ---- gated blocks ----
    for (int l = 0; l < LL; ++l) {
        const float* wih = gru_wih + (size_t)l * 3 * CD * CD;
        const float* whh = gru_whh + (size_t)l * 3 * CD * CD;
        const float* bih = gru_bih + (size_t)l * 3 * CD;
        const float* bhh = gru_bhh + (size_t)l * 3 * CD;
        for (int i = 0; i < 2; ++i) {
            const float* Wg = ggc_w + ((size_t)l * 2 + i) * CD * CD;
            gemm_f32<false, false><<<dim3(gmx, CD / 64), 256, 0, stream>>>(g, Wg, nullptr, m, NN, CD, CD);
            agg_plain_kernel<<<NN, 256, 0, stream>>>(m, offsets, srcs, abuf);
            for (int r0 = 0; r0 < NN; r0 += CH) {
                int rows = NN - r0; if (rows > CH) rows = CH;
                dim3 gg((rows + 127) / 128, 3 * CD / 64);
                gemm_f32<true, true><<<gg, 256, 0, stream>>>(abuf + (size_t)r0 * CD, wih, bih, gi, rows, 3 * CD, CD);
                gemm_f32<true, true><<<gg, 256, 0, stream>>>(g + (size_t)r0 * CD, whh, bhh, gh, rows, 3 * CD, CD);
                gru_kernel<<<(rows * CD + 255) / 256, 256, 0, stream>>>(gi, gh, g, rows, r0);
            }
        }
        hipMemsetAsync(sums, 0, 2 * GG * CD * 4, stream);
        gelu_gn_partial_kernel<<<nb_gn, 256, 0, stream>>>(g, batch, m, sums, sumsq);
        gn_finalize_kernel<<<(GG * CD + 255) / 256, 256, 0, stream>>>(sums, sumsq, cntg, gn_w + l * CD, gn_ms + l * CD, scaleA, shiftB);
        gn_apply_kernel<true><<<nthr_nc, 256, 0, stream>>>(m, batch, scaleA, shiftB, gn_b + l * CD, h, g);
    }

    // ---- final linear ----
    gemm_f32<true, true><<<dim3(gmx, OUTD / 64), 256, 0, stream>>>(h, lin_w, lin_b, outp, NN, OUTD, CD);
}

// Round 3
// 1317.827 us; speedup vs baseline: 2.1207x; 2.1207x over previous
//
#include <hip/hip_runtime.h>
#include <math.h>

typedef unsigned short u16;
typedef _Float16 f16;
typedef __attribute__((ext_vector_type(8))) _Float16 f16x8;
typedef __attribute__((ext_vector_type(4))) float f32x4;

constexpr int NN   = 20000;
constexpr int EE   = 320000;
constexpr int CD   = 256;
constexpr int IND  = 128;
constexpr int OUTD = 128;
constexpr int LL   = 3;
constexpr int GG   = 16;
constexpr float EPSV = 1e-5f;

__device__ __forceinline__ u16 f2h(float f) {
    union { f16 h; u16 u; } v; v.h = (f16)f; return v.u;
}
__device__ __forceinline__ float h2f(u16 u) {
    union { u16 u; f16 h; } v; v.u = u; return (float)v.h;
}

// ---------------------------------------------------------------------------
// CSR build
// ---------------------------------------------------------------------------
__global__ void hist_edges_kernel(const int* __restrict__ dst, int* __restrict__ counts) {
    int e = blockIdx.x * blockDim.x + threadIdx.x;
    if (e < EE) atomicAdd(&counts[dst[e]], 1);
}

// per-block LDS histogram -> 16 global atomics per block
__global__ void hist_batch_kernel(const int* __restrict__ batch, int* __restrict__ cntg) {
    __shared__ int loc[GG];
    if (threadIdx.x < GG) loc[threadIdx.x] = 0;
    __syncthreads();
    for (int i = blockIdx.x * blockDim.x + threadIdx.x; i < NN; i += gridDim.x * blockDim.x)
        atomicAdd(&loc[batch[i]], 1);
    __syncthreads();
    if (threadIdx.x < GG) atomicAdd(&cntg[threadIdx.x], loc[threadIdx.x]);
}

__global__ __launch_bounds__(1024) void scan_kernel(const int* __restrict__ counts,
                                                    int* __restrict__ offsets,
                                                    float* __restrict__ dinv) {
    __shared__ int ls[1024];
    int t = threadIdx.x;
    const int CHK = (NN + 1023) / 1024;
    int begin = t * CHK;
    int end   = begin + CHK; if (end > NN) end = NN;
    int s = 0;
    for (int i = begin; i < end && i < NN; ++i) s += counts[i];
    ls[t] = s;
    __syncthreads();
    for (int off = 1; off < 1024; off <<= 1) {
        int v = (t >= off) ? ls[t - off] : 0;
        __syncthreads();
        ls[t] += v;
        __syncthreads();
    }
    int run = ls[t] - s;
    for (int i = begin; i < end && i < NN; ++i) {
        offsets[i] = run;
        int c = counts[i];
        run += c;
        dinv[i] = rsqrtf((float)(c + 1));
    }
    if (t == 1023) offsets[NN] = run;
}

__global__ void fill_kernel(const int* __restrict__ src, const int* __restrict__ dst,
                            const int* __restrict__ offsets, int* __restrict__ cursor,
                            const float* __restrict__ dinv,
                            int* __restrict__ srcs, float* __restrict__ wts) {
    int e = blockIdx.x * blockDim.x + threadIdx.x;
    if (e >= EE) return;
    int d = dst[e];
    int p = atomicAdd(&cursor[d], 1);
    int pos = offsets[d] + p;
    int s = src[e];
    srcs[pos] = s;
    wts[pos]  = dinv[s];
}

// ---------------------------------------------------------------------------
// Conversions (f32 -> f16 bits)
// ---------------------------------------------------------------------------
__global__ void f2h_kernel(const float* __restrict__ in, u16* __restrict__ out, int n4) {
    int i = blockIdx.x * blockDim.x + threadIdx.x;
    if (i >= n4) return;
    float4 v = ((const float4*)in)[i];
    ushort4 o;
    o.x = f2h(v.x); o.y = f2h(v.y); o.z = f2h(v.z); o.w = f2h(v.w);
    ((ushort4*)out)[i] = o;
}

// ggc_w: 6 matrices [K=256][N=256] -> f16 [N][K]
__global__ void tconv_kernel(const float* __restrict__ in, u16* __restrict__ out) {
    int i = blockIdx.x * blockDim.x + threadIdx.x;   // 6*65536
    if (i >= 6 * 65536) return;
    int mat = i >> 16, r = (i >> 8) & 255, c = i & 255;
    out[i] = f2h(in[(mat << 16) + (c << 8) + r]);
}

// ---------------------------------------------------------------------------
// f16 MFMA GEMM: C[M,N] = A[M,K] * W^T  (W stored [N,K] f16) (+bias)
// 128x128 tile, BK=32, 4 waves (2x2 of 64x64), global_load_lds width 16.
// ---------------------------------------------------------------------------
template<bool BIAS, bool OUTH>
__global__ __launch_bounds__(256) void gemm_mfma(const u16* __restrict__ A,
                                                 const u16* __restrict__ B,
                                                 const float* __restrict__ bias,
                                                 float* __restrict__ Cf,
                                                 u16* __restrict__ Ch,
                                                 int M, int N, int K) {
    __shared__ u16 As[128 * 32];
    __shared__ u16 Bs[128 * 32];
    const int tid  = threadIdx.x;
    const int lane = tid & 63;
    const int wave = tid >> 6;
    const int wr = wave >> 1, wc = wave & 1;
    const int bm = blockIdx.x * 128, bn = blockIdx.y * 128;

    f32x4 acc[4][4];
    #pragma unroll
    for (int i = 0; i < 4; ++i)
        #pragma unroll
        for (int j = 0; j < 4; ++j) acc[i][j] = (f32x4)0.f;

    const int srow = tid >> 2;            // 0..63
    const int skc  = (tid & 3) * 8;       // k element offset

    const int fr = lane & 15;
    const int kg = (lane >> 4) * 8;

    for (int k0 = 0; k0 < K; k0 += 32) {
        #pragma unroll
        for (int it = 0; it < 2; ++it) {
            int row  = srow + it * 64;
            int arow = bm + row; if (arow >= M) arow = M - 1;
            const u16* ga = &A[(size_t)arow * K + k0 + skc];
            const u16* gb = &B[(size_t)(bn + row) * K + k0 + skc];
            __builtin_amdgcn_global_load_lds(
                (const __attribute__((address_space(1))) void*)ga,
                (__attribute__((address_space(3))) void*)((char*)As + it * 4096 + tid * 16),
                16, 0, 0);
            __builtin_amdgcn_global_load_lds(
                (const __attribute__((address_space(1))) void*)gb,
                (__attribute__((address_space(3))) void*)((char*)Bs + it * 4096 + tid * 16),
                16, 0, 0);
        }
        __syncthreads();

        f16x8 af[4], bfr[4];
        #pragma unroll
        for (int m2 = 0; m2 < 4; ++m2)
            af[m2] = *(const f16x8*)&As[(wr * 64 + m2 * 16 + fr) * 32 + kg];
        #pragma unroll
        for (int n2 = 0; n2 < 4; ++n2)
            bfr[n2] = *(const f16x8*)&Bs[(wc * 64 + n2 * 16 + fr) * 32 + kg];
        #pragma unroll
        for (int m2 = 0; m2 < 4; ++m2)
            #pragma unroll
            for (int n2 = 0; n2 < 4; ++n2)
                acc[m2][n2] = __builtin_amdgcn_mfma_f32_16x16x32_f16(af[m2], bfr[n2], acc[m2][n2], 0, 0, 0);
        __syncthreads();
    }

    const int fq = lane >> 4;
    float bv[4];
    if (BIAS) {
        #pragma unroll
        for (int n2 = 0; n2 < 4; ++n2) bv[n2] = bias[bn + wc * 64 + n2 * 16 + fr];
    }
    #pragma unroll
    for (int m2 = 0; m2 < 4; ++m2) {
        int rbase = bm + wr * 64 + m2 * 16 + fq * 4;
        #pragma unroll
        for (int n2 = 0; n2 < 4; ++n2) {
            int col = bn + wc * 64 + n2 * 16 + fr;
            #pragma unroll
            for (int j = 0; j < 4; ++j) {
                int r = rbase + j;
                if (r < M) {
                    float v = acc[m2][n2][j];
                    if (BIAS) v += bv[n2];
                    if (OUTH) Ch[(size_t)r * N + col] = f2h(v);
                    else      Cf[(size_t)r * N + col] = v;
                }
            }
        }
    }
}

// ---------------------------------------------------------------------------
// Edge aggregation (f16 in, CSR per-node)
// ---------------------------------------------------------------------------
__global__ __launch_bounds__(256) void gcn_agg_kernel(const u16* __restrict__ m,
                                                      const int* __restrict__ offsets,
                                                      const int* __restrict__ srcs,
                                                      const float* __restrict__ wts,
                                                      const float* __restrict__ dinv,
                                                      const float* __restrict__ bias,
                                                      u16* __restrict__ outp) {
    int v = blockIdx.x;
    int c = threadIdx.x;
    float dv = dinv[v];
    int o0 = offsets[v], o1 = offsets[v + 1];
    float acc = 0.f;
    for (int o = o0; o < o1; ++o)
        acc += wts[o] * h2f(m[(size_t)srcs[o] * CD + c]);
    float val = dv * acc + dv * dv * h2f(m[(size_t)v * CD + c]) + bias[c];
    outp[(size_t)v * CD + c] = f2h(val);
}

__global__ __launch_bounds__(256) void agg_plain_kernel(const u16* __restrict__ m,
                                                        const int* __restrict__ offsets,
                                                        const int* __restrict__ srcs,
                                                        u16* __restrict__ outp) {
    int v = blockIdx.x;
    int c = threadIdx.x;
    int o0 = offsets[v], o1 = offsets[v + 1];
    float acc = 0.f;
    for (int o = o0; o < o1; ++o)
        acc += h2f(m[(size_t)srcs[o] * CD + c]);
    outp[(size_t)v * CD + c] = f2h(acc);
}

// ---------------------------------------------------------------------------
// GraphNorm
// ---------------------------------------------------------------------------
__global__ __launch_bounds__(256) void gn_partial_kernel(const u16* __restrict__ x,
                                                         const int* __restrict__ batch,
                                                         float* __restrict__ sums,
                                                         float* __restrict__ sumsq) {
    int c = threadIdx.x;
    int node0 = blockIdx.x * 64;
    if (node0 >= NN) return;
    int node1 = node0 + 64; if (node1 > NN) node1 = NN;
    int gcur = batch[node0];
    float s = 0.f, q = 0.f;
    for (int v = node0; v < node1; ++v) {
        int gb = batch[v];
        if (gb != gcur) {
            atomicAdd(&sums[gcur * CD + c], s);
            atomicAdd(&sumsq[gcur * CD + c], q);
            s = 0.f; q = 0.f; gcur = gb;
        }
        float val = h2f(x[(size_t)v * CD + c]);
        s += val; q += val * val;
    }
    atomicAdd(&sums[gcur * CD + c], s);
    atomicAdd(&sumsq[gcur * CD + c], q);
}

// gelu(exact) on f32 g, write f16 um + partial sums
__global__ __launch_bounds__(256) void gelu_gn_partial_kernel(const float* __restrict__ x,
                                                              const int* __restrict__ batch,
                                                              u16* __restrict__ um,
                                                              float* __restrict__ sums,
                                                              float* __restrict__ sumsq) {
    int c = threadIdx.x;
    int node0 = blockIdx.x * 64;
    if (node0 >= NN) return;
    int node1 = node0 + 64; if (node1 > NN) node1 = NN;
    int gcur = batch[node0];
    float s = 0.f, q = 0.f;
    for (int v = node0; v < node1; ++v) {
        int gb = batch[v];
        if (gb != gcur) {
            atomicAdd(&sums[gcur * CD + c], s);
            atomicAdd(&sumsq[gcur * CD + c], q);
            s = 0.f; q = 0.f; gcur = gb;
        }
        float xv = x[(size_t)v * CD + c];
        float val = 0.5f * xv * (1.f + erff(xv * 0.70710678118654752f));
        um[(size_t)v * CD + c] = f2h(val);
        s += val; q += val * val;
    }
    atomicAdd(&sums[gcur * CD + c], s);
    atomicAdd(&sumsq[gcur * CD + c], q);
}

__global__ void gn_finalize_kernel(const float* __restrict__ sums,
                                   const float* __restrict__ sumsq,
                                   const int* __restrict__ cntg,
                                   const float* __restrict__ w,
                                   const float* __restrict__ ms,
                                   float* __restrict__ scaleA,
                                   float* __restrict__ shiftB) {
    int i = blockIdx.x * blockDim.x + threadIdx.x;
    if (i >= GG * CD) return;
    int g = i / CD, c = i % CD;
    float cnt  = fmaxf((float)cntg[g], 1.0f);
    float mean = sums[i] / cnt;
    float ex2  = sumsq[i] / cnt;
    float msm  = ms[c] * mean;
    float var  = ex2 - 2.f * msm * mean + msm * msm;
    scaleA[i] = w[c] * rsqrtf(var + EPSV);
    shiftB[i] = msm;
}

// apply norm (f16 x in); writes h f32, g f32, g_h f16.  RES: h += normed
template<bool RES>
__global__ void gn_apply_kernel(const u16* __restrict__ x,
                                const int* __restrict__ batch,
                                const float* __restrict__ scaleA,
                                const float* __restrict__ shiftB,
                                const float* __restrict__ bvec,
                                float* __restrict__ h,
                                float* __restrict__ g,
                                u16* __restrict__ g_h) {
    int i = blockIdx.x * blockDim.x + threadIdx.x;   // over NN*64
    if (i >= NN * (CD / 4)) return;
    int v = i >> 6, c4 = (i & 63) << 2;
    int gb = batch[v];
    size_t idx = (size_t)v * CD + c4;
    ushort4 xv = *(const ushort4*)&x[idx];
    float4 sA = *(const float4*)&scaleA[gb * CD + c4];
    float4 sB = *(const float4*)&shiftB[gb * CD + c4];
    float4 bb = *(const float4*)&bvec[c4];
    float4 val;
    val.x = (h2f(xv.x) - sB.x) * sA.x + bb.x;
    val.y = (h2f(xv.y) - sB.y) * sA.y + bb.y;
    val.z = (h2f(xv.z) - sB.z) * sA.z + bb.z;
    val.w = (h2f(xv.w) - sB.w) * sA.w + bb.w;
    if (RES) {
        float4 hv = *(const float4*)&h[idx];
        val.x += hv.x; val.y += hv.y; val.z += hv.z; val.w += hv.w;
    }
    *(float4*)&h[idx] = val;
    *(float4*)&g[idx] = val;
    ushort4 ov; ov.x = f2h(val.x); ov.y = f2h(val.y); ov.z = f2h(val.z); ov.w = f2h(val.w);
    *(ushort4*)&g_h[idx] = ov;
}

// ---------------------------------------------------------------------------
// GRU elementwise (vectorized x4); updates g f32 + g_h f16
// ---------------------------------------------------------------------------
__global__ void gru_kernel(const float* __restrict__ gi, const float* __restrict__ gh,
                           float* __restrict__ g, u16* __restrict__ g_h,
                           int rows, int r0) {
    int i = blockIdx.x * blockDim.x + threadIdx.x;   // over rows*64
    if (i >= rows * (CD / 4)) return;
    int rr = i >> 6, c4 = (i & 63) << 2;
    const float* gip = gi + (size_t)rr * 3 * CD + c4;
    const float* ghp = gh + (size_t)rr * 3 * CD + c4;
    float4 ir = *(const float4*)gip;
    float4 iz = *(const float4*)(gip + CD);
    float4 in_ = *(const float4*)(gip + 2 * CD);
    float4 hr = *(const float4*)ghp;
    float4 hz = *(const float4*)(ghp + CD);
    float4 hn = *(const float4*)(ghp + 2 * CD);
    size_t gidx = (size_t)(r0 + rr) * CD + c4;
    float4 hold = *(const float4*)&g[gidx];
    float4 outv; ushort4 ob;
    #pragma unroll
    for (int t = 0; t < 4; ++t) {
        float irt = (&ir.x)[t], izt = (&iz.x)[t], int_ = (&in_.x)[t];
        float hrt = (&hr.x)[t], hzt = (&hz.x)[t], hnt = (&hn.x)[t];
        float r = 1.f / (1.f + expf(-(irt + hrt)));
        float z = 1.f / (1.f + expf(-(izt + hzt)));
        float nval = tanhf(int_ + r * hnt);
        float res = (1.f - z) * nval + z * (&hold.x)[t];
        (&outv.x)[t] = res;
        (&ob.x)[t] = f2h(res);
    }
    *(float4*)&g[gidx] = outv;
    *(ushort4*)&g_h[gidx] = ob;
}

// ---------------------------------------------------------------------------
// Host
// ---------------------------------------------------------------------------
extern "C" void kernel_launch(void* const* d_in, const int* in_sizes, int n_in,
                              void* d_out, int out_size, void* d_ws, size_t ws_size,
                              hipStream_t stream) {
    const float* x      = (const float*)d_in[0];
    const int*   ei     = (const int*)d_in[1];
    const int*   batch  = (const int*)d_in[2];
    const float* gcn_w  = (const float*)d_in[3];
    const float* gcn_b  = (const float*)d_in[4];
    const float* gn0_w  = (const float*)d_in[5];
    const float* gn0_b  = (const float*)d_in[6];
    const float* gn0_ms = (const float*)d_in[7];
    const float* ggc_w  = (const float*)d_in[8];
    const float* gru_wih = (const float*)d_in[9];
    const float* gru_whh = (const float*)d_in[10];
    const float* gru_bih = (const float*)d_in[11];
    const float* gru_bhh = (const float*)d_in[12];
    const float* gn_w   = (const float*)d_in[13];
    const float* gn_b   = (const float*)d_in[14];
    const float* gn_ms  = (const float*)d_in[15];
    const float* lin_w  = (const float*)d_in[16];
    const float* lin_b  = (const float*)d_in[17];
    float* outp = (float*)d_out;

    const int* srcv = ei;
    const int* dstv = ei + EE;

    char* base = (char*)d_ws;
    size_t off = 0;
    auto alloc = [&](size_t bytes) -> void* {
        void* p = base + off;
        off = (off + bytes + 255) & ~(size_t)255;
        return p;
    };

    int*   counts  = (int*)alloc(NN * 4);
    int*   cursor  = (int*)alloc(NN * 4);
    int*   cntg    = (int*)alloc(GG * 4);
    size_t zero_end = off;
    int*   offsets = (int*)alloc((NN + 1) * 4);
    int*   srcs    = (int*)alloc((size_t)EE * 4);
    float* wts     = (float*)alloc((size_t)EE * 4);
    float* dinv    = (float*)alloc(NN * 4);
    float* sums    = (float*)alloc(GG * CD * 4);
    float* sumsq   = (float*)alloc(GG * CD * 4);
    float* scaleA  = (float*)alloc(GG * CD * 4);
    float* shiftB  = (float*)alloc(GG * CD * 4);
    // f16 weights
    u16* gcn_wt = (u16*)alloc((size_t)CD * IND * 2);
    u16* ggc_wt = (u16*)alloc((size_t)6 * CD * CD * 2);
    u16* wih_h  = (u16*)alloc((size_t)LL * 3 * CD * CD * 2);
    u16* whh_h  = (u16*)alloc((size_t)LL * 3 * CD * CD * 2);
    u16* lin_wt = (u16*)alloc((size_t)OUTD * CD * 2);
    // activations
    u16*   x_h   = (u16*)alloc((size_t)NN * IND * 2);
    float* g     = (float*)alloc((size_t)NN * CD * 4);
    u16*   g_h   = (u16*)alloc((size_t)NN * CD * 2);
    float* h     = (float*)alloc((size_t)NN * CD * 4);
    u16*   m_h   = (u16*)alloc((size_t)NN * CD * 2);
    u16*   a_h   = (u16*)alloc((size_t)NN * CD * 2);

    size_t rem = (ws_size > off + 512) ? (ws_size - off - 512) : 0;
    size_t per_row = (size_t)2 * 3 * CD * 4;
    int CH = (int)(rem / per_row);
    if (CH > NN) CH = NN;
    if (CH < 256) CH = 256;
    float* gi = (float*)alloc((size_t)CH * 3 * CD * 4);
    float* gh = (float*)alloc((size_t)CH * 3 * CD * 4);

    // ---- CSR build + per-graph counts ----
    hipMemsetAsync(counts, 0, zero_end, stream);
    hist_edges_kernel<<<(EE + 255) / 256, 256, 0, stream>>>(dstv, counts);
    hist_batch_kernel<<<64, 256, 0, stream>>>(batch, cntg);
    scan_kernel<<<1, 1024, 0, stream>>>(counts, offsets, dinv);
    fill_kernel<<<(EE + 255) / 256, 256, 0, stream>>>(srcv, dstv, offsets, cursor, dinv, srcs, wts);

    // ---- weight + input conversions ----
    f2h_kernel<<<(NN * IND / 4 + 255) / 256, 256, 0, stream>>>(x, x_h, NN * IND / 4);
    f2h_kernel<<<(CD * IND / 4 + 255) / 256, 256, 0, stream>>>(gcn_w, gcn_wt, CD * IND / 4);
    tconv_kernel<<<(6 * 65536 + 255) / 256, 256, 0, stream>>>(ggc_w, ggc_wt);
    f2h_kernel<<<(LL * 3 * CD * CD / 4 + 255) / 256, 256, 0, stream>>>(gru_wih, wih_h, LL * 3 * CD * CD / 4);
    f2h_kernel<<<(LL * 3 * CD * CD / 4 + 255) / 256, 256, 0, stream>>>(gru_whh, whh_h, LL * 3 * CD * CD / 4);
    f2h_kernel<<<(OUTD * CD / 4 + 255) / 256, 256, 0, stream>>>(lin_w, lin_wt, OUTD * CD / 4);

    const int gmx = (NN + 127) / 128;      // 157
    const int nb_gn = (NN + 63) / 64;      // 313
    const int nv4 = (NN * (CD / 4) + 255) / 256;

    // ---- GCNConv ----
    gemm_mfma<false, true><<<dim3(gmx, CD / 128), 256, 0, stream>>>(x_h, gcn_wt, nullptr, nullptr, m_h, NN, CD, IND);
    gcn_agg_kernel<<<NN, 256, 0, stream>>>(m_h, offsets, srcs, wts, dinv, gcn_b, a_h);

    hipMemsetAsync(sums, 0, 2 * GG * CD * 4, stream);
    gn_partial_kernel<<<nb_gn, 256, 0, stream>>>(a_h, batch, sums, sumsq);
    gn_finalize_kernel<<<(GG * CD + 255) / 256, 256, 0, stream>>>(sums, sumsq, cntg, gn0_w, gn0_ms, scaleA, shiftB);
    gn_apply_kernel<false><<<nv4, 256, 0, stream>>>(a_h, batch, scaleA, shiftB, gn0_b, h, g, g_h);

    // ---- gated blocks ----
    for (int l = 0; l < LL; ++l) {
        const u16* wih = wih_h + (size_t)l * 3 * CD * CD;
        const u16* whh = whh_h + (size_t)l * 3 * CD * CD;
        const float* bih = gru_bih + (size_t)l * 3 * CD;
        const float* bhh = gru_bhh + (size_t)l * 3 * CD;
        for (int i = 0; i < 2; ++i) {
            const u16* Wg = ggc_wt + ((size_t)l * 2 + i) * CD * CD;
            gemm_mfma<false, true><<<dim3(gmx, CD / 128), 256, 0, stream>>>(g_h, Wg, nullptr, nullptr, m_h, NN, CD, CD);
            agg_plain_kernel<<<NN, 256, 0, stream>>>(m_h, offsets, srcs, a_h);
            for (int r0 = 0; r0 < NN; r0 += CH) {
                int rows = NN - r0; if (rows > CH) rows = CH;
                dim3 gg((rows + 127) / 128, 3 * CD / 128);
                gemm_mfma<true, false><<<gg, 256, 0, stream>>>(a_h + (size_t)r0 * CD, wih, bih, gi, nullptr, rows, 3 * CD, CD);
                gemm_mfma<true, false><<<gg, 256, 0, stream>>>(g_h + (size_t)r0 * CD, whh, bhh, gh, nullptr, rows, 3 * CD, CD);
                gru_kernel<<<(rows * (CD / 4) + 255) / 256, 256, 0, stream>>>(gi, gh, g, g_h, rows, r0);
            }
        }
        hipMemsetAsync(sums, 0, 2 * GG * CD * 4, stream);
        gelu_gn_partial_kernel<<<nb_gn, 256, 0, stream>>>(g, batch, m_h, sums, sumsq);
        gn_finalize_kernel<<<(GG * CD + 255) / 256, 256, 0, stream>>>(sums, sumsq, cntg, gn_w + l * CD, gn_ms + l * CD, scaleA, shiftB);
        gn_apply_kernel<true><<<nv4, 256, 0, stream>>>(m_h, batch, scaleA, shiftB, gn_b + l * CD, h, g, g_h);
    }

    // ---- final linear: convert h -> f16 (reuse a_h), then MFMA ----
    f2h_kernel<<<(NN * CD / 4 + 255) / 256, 256, 0, stream>>>(h, a_h, NN * CD / 4);
    gemm_mfma<true, false><<<dim3(gmx, OUTD / 128), 256, 0, stream>>>(a_h, lin_wt, lin_b, outp, nullptr, NN, OUTD, CD);
}

// Round 4
// 1023.638 us; speedup vs baseline: 2.7302x; 1.2874x over previous
//
#include <hip/hip_runtime.h>
#include <math.h>

typedef unsigned short u16;
typedef _Float16 f16;
typedef __attribute__((ext_vector_type(8))) _Float16 f16x8;
typedef __attribute__((ext_vector_type(4))) float f32x4;

constexpr int NN   = 20000;
constexpr int EE   = 320000;
constexpr int CD   = 256;
constexpr int IND  = 128;
constexpr int OUTD = 128;
constexpr int LL   = 3;
constexpr int GG   = 16;
constexpr float EPSV = 1e-5f;

__device__ __forceinline__ u16 f2h(float f) {
    union { f16 h; u16 u; } v; v.h = (f16)f; return v.u;
}
__device__ __forceinline__ float h2f(u16 u) {
    union { u16 u; f16 h; } v; v.u = u; return (float)v.h;
}

// ---------------------------------------------------------------------------
// CSR build
// ---------------------------------------------------------------------------
__global__ void hist_edges_kernel(const int* __restrict__ dst, int* __restrict__ counts) {
    int e = blockIdx.x * blockDim.x + threadIdx.x;
    if (e < EE) atomicAdd(&counts[dst[e]], 1);
}

__global__ void hist_batch_kernel(const int* __restrict__ batch, int* __restrict__ cntg) {
    __shared__ int loc[GG];
    if (threadIdx.x < GG) loc[threadIdx.x] = 0;
    __syncthreads();
    for (int i = blockIdx.x * blockDim.x + threadIdx.x; i < NN; i += gridDim.x * blockDim.x)
        atomicAdd(&loc[batch[i]], 1);
    __syncthreads();
    if (threadIdx.x < GG) atomicAdd(&cntg[threadIdx.x], loc[threadIdx.x]);
}

__global__ __launch_bounds__(1024) void scan_kernel(const int* __restrict__ counts,
                                                    int* __restrict__ offsets,
                                                    float* __restrict__ dinv) {
    __shared__ int ls[1024];
    int t = threadIdx.x;
    const int CHK = (NN + 1023) / 1024;
    int begin = t * CHK;
    int end   = begin + CHK; if (end > NN) end = NN;
    int s = 0;
    for (int i = begin; i < end && i < NN; ++i) s += counts[i];
    ls[t] = s;
    __syncthreads();
    for (int off = 1; off < 1024; off <<= 1) {
        int v = (t >= off) ? ls[t - off] : 0;
        __syncthreads();
        ls[t] += v;
        __syncthreads();
    }
    int run = ls[t] - s;
    for (int i = begin; i < end && i < NN; ++i) {
        offsets[i] = run;
        int c = counts[i];
        run += c;
        dinv[i] = rsqrtf((float)(c + 1));
    }
    if (t == 1023) offsets[NN] = run;
}

__global__ void fill_kernel(const int* __restrict__ src, const int* __restrict__ dst,
                            const int* __restrict__ offsets, int* __restrict__ cursor,
                            const float* __restrict__ dinv,
                            int* __restrict__ srcs, float* __restrict__ wts) {
    int e = blockIdx.x * blockDim.x + threadIdx.x;
    if (e >= EE) return;
    int d = dst[e];
    int p = atomicAdd(&cursor[d], 1);
    int pos = offsets[d] + p;
    int s = src[e];
    srcs[pos] = s;
    wts[pos]  = dinv[s];
}

// ---------------------------------------------------------------------------
// Conversions (f32 -> f16 bits)
// ---------------------------------------------------------------------------
__global__ void f2h_kernel(const float* __restrict__ in, u16* __restrict__ out, int n4) {
    int i = blockIdx.x * blockDim.x + threadIdx.x;
    if (i >= n4) return;
    float4 v = ((const float4*)in)[i];
    ushort4 o;
    o.x = f2h(v.x); o.y = f2h(v.y); o.z = f2h(v.z); o.w = f2h(v.w);
    ((ushort4*)out)[i] = o;
}

// ---------------------------------------------------------------------------
// f16 MFMA GEMM: C[M,N] = A[M,K] * B^T  (B stored [N,K] f16) (+bias)
// 128x128 tile, BK=32, 4 waves (2x2 of 64x64), global_load_lds width 16.
// ---------------------------------------------------------------------------
template<bool BIAS, bool OUTH>
__global__ __launch_bounds__(256) void gemm_mfma(const u16* __restrict__ A,
                                                 const u16* __restrict__ B,
                                                 const float* __restrict__ bias,
                                                 float* __restrict__ Cf,
                                                 u16* __restrict__ Ch,
                                                 int M, int N, int K) {
    __shared__ u16 As[128 * 32];
    __shared__ u16 Bs[128 * 32];
    const int tid  = threadIdx.x;
    const int lane = tid & 63;
    const int wave = tid >> 6;
    const int wr = wave >> 1, wc = wave & 1;
    const int bm = blockIdx.x * 128, bn = blockIdx.y * 128;

    f32x4 acc[4][4];
    #pragma unroll
    for (int i = 0; i < 4; ++i)
        #pragma unroll
        for (int j = 0; j < 4; ++j) acc[i][j] = (f32x4)0.f;

    const int srow = tid >> 2;            // 0..63
    const int skc  = (tid & 3) * 8;       // k element offset

    const int fr = lane & 15;
    const int kg = (lane >> 4) * 8;

    for (int k0 = 0; k0 < K; k0 += 32) {
        #pragma unroll
        for (int it = 0; it < 2; ++it) {
            int row  = srow + it * 64;
            int arow = bm + row; if (arow >= M) arow = M - 1;
            const u16* ga = &A[(size_t)arow * K + k0 + skc];
            const u16* gb = &B[(size_t)(bn + row) * K + k0 + skc];
            __builtin_amdgcn_global_load_lds(
                (const __attribute__((address_space(1))) void*)ga,
                (__attribute__((address_space(3))) void*)((char*)As + it * 4096 + tid * 16),
                16, 0, 0);
            __builtin_amdgcn_global_load_lds(
                (const __attribute__((address_space(1))) void*)gb,
                (__attribute__((address_space(3))) void*)((char*)Bs + it * 4096 + tid * 16),
                16, 0, 0);
        }
        __syncthreads();

        f16x8 af[4], bfr[4];
        #pragma unroll
        for (int m2 = 0; m2 < 4; ++m2)
            af[m2] = *(const f16x8*)&As[(wr * 64 + m2 * 16 + fr) * 32 + kg];
        #pragma unroll
        for (int n2 = 0; n2 < 4; ++n2)
            bfr[n2] = *(const f16x8*)&Bs[(wc * 64 + n2 * 16 + fr) * 32 + kg];
        #pragma unroll
        for (int m2 = 0; m2 < 4; ++m2)
            #pragma unroll
            for (int n2 = 0; n2 < 4; ++n2)
                acc[m2][n2] = __builtin_amdgcn_mfma_f32_16x16x32_f16(af[m2], bfr[n2], acc[m2][n2], 0, 0, 0);
        __syncthreads();
    }

    const int fq = lane >> 4;
    float bv[4];
    if (BIAS) {
        #pragma unroll
        for (int n2 = 0; n2 < 4; ++n2) bv[n2] = bias[bn + wc * 64 + n2 * 16 + fr];
    }
    #pragma unroll
    for (int m2 = 0; m2 < 4; ++m2) {
        int rbase = bm + wr * 64 + m2 * 16 + fq * 4;
        #pragma unroll
        for (int n2 = 0; n2 < 4; ++n2) {
            int col = bn + wc * 64 + n2 * 16 + fr;
            #pragma unroll
            for (int j = 0; j < 4; ++j) {
                int r = rbase + j;
                if (r < M) {
                    float v = acc[m2][n2][j];
                    if (BIAS) v += bv[n2];
                    if (OUTH) Ch[(size_t)r * N + col] = f2h(v);
                    else      Cf[(size_t)r * N + col] = v;
                }
            }
        }
    }
}

// ---------------------------------------------------------------------------
// Edge aggregation, ILP version: 256 thr = NG edge-groups x LPE lanes (8B/lane)
// GCN: out = dinv[v]*sum(wts*feat[src]) + dinv[v]^2*feat[v]; else plain sum.
// ---------------------------------------------------------------------------
template<int CHN, bool GCN>
__global__ __launch_bounds__(256) void agg_kernel(const u16* __restrict__ feat,
                                                  const int* __restrict__ offsets,
                                                  const int* __restrict__ srcs,
                                                  const float* __restrict__ wts,
                                                  const float* __restrict__ dinv,
                                                  u16* __restrict__ outp) {
    constexpr int LPE = CHN / 4;      // lanes per edge
    constexpr int NG  = 256 / LPE;    // concurrent edges
    __shared__ float red[NG * CHN];
    const int v   = blockIdx.x;
    const int grp = threadIdx.x / LPE;
    const int ln  = threadIdx.x % LPE;
    const int o0 = offsets[v], o1 = offsets[v + 1];
    float ax = 0.f, ay = 0.f, az = 0.f, aw = 0.f;
    for (int o = o0 + grp; o < o1; o += NG) {
        int s = srcs[o];
        float w = GCN ? wts[o] : 1.0f;
        ushort4 mv = *(const ushort4*)&feat[(size_t)s * CHN + ln * 4];
        ax += w * h2f(mv.x); ay += w * h2f(mv.y);
        az += w * h2f(mv.z); aw += w * h2f(mv.w);
    }
    float4 a4 = make_float4(ax, ay, az, aw);
    *(float4*)&red[grp * CHN + ln * 4] = a4;
    __syncthreads();
    if (threadIdx.x < LPE) {
        int l = threadIdx.x;
        float4 tot = *(const float4*)&red[l * 4];
        #pragma unroll
        for (int q = 1; q < NG; ++q) {
            float4 p = *(const float4*)&red[q * CHN + l * 4];
            tot.x += p.x; tot.y += p.y; tot.z += p.z; tot.w += p.w;
        }
        if (GCN) {
            float dv = dinv[v];
            ushort4 sv = *(const ushort4*)&feat[(size_t)v * CHN + l * 4];
            tot.x = dv * tot.x + dv * dv * h2f(sv.x);
            tot.y = dv * tot.y + dv * dv * h2f(sv.y);
            tot.z = dv * tot.z + dv * dv * h2f(sv.z);
            tot.w = dv * tot.w + dv * dv * h2f(sv.w);
        }
        ushort4 ov;
        ov.x = f2h(tot.x); ov.y = f2h(tot.y); ov.z = f2h(tot.z); ov.w = f2h(tot.w);
        *(ushort4*)&outp[(size_t)v * CHN + l * 4] = ov;
    }
}

// ---------------------------------------------------------------------------
// GraphNorm
// ---------------------------------------------------------------------------
__global__ __launch_bounds__(256) void gn_partial_kernel(const u16* __restrict__ x,
                                                         const int* __restrict__ batch,
                                                         float* __restrict__ sums,
                                                         float* __restrict__ sumsq) {
    int c = threadIdx.x;
    int node0 = blockIdx.x * 64;
    if (node0 >= NN) return;
    int node1 = node0 + 64; if (node1 > NN) node1 = NN;
    int gcur = batch[node0];
    float s = 0.f, q = 0.f;
    for (int v = node0; v < node1; ++v) {
        int gb = batch[v];
        if (gb != gcur) {
            atomicAdd(&sums[gcur * CD + c], s);
            atomicAdd(&sumsq[gcur * CD + c], q);
            s = 0.f; q = 0.f; gcur = gb;
        }
        float val = h2f(x[(size_t)v * CD + c]);
        s += val; q += val * val;
    }
    atomicAdd(&sums[gcur * CD + c], s);
    atomicAdd(&sumsq[gcur * CD + c], q);
}

// gelu(exact) on f32 g, write f16 um + partial sums
__global__ __launch_bounds__(256) void gelu_gn_partial_kernel(const float* __restrict__ x,
                                                              const int* __restrict__ batch,
                                                              u16* __restrict__ um,
                                                              float* __restrict__ sums,
                                                              float* __restrict__ sumsq) {
    int c = threadIdx.x;
    int node0 = blockIdx.x * 64;
    if (node0 >= NN) return;
    int node1 = node0 + 64; if (node1 > NN) node1 = NN;
    int gcur = batch[node0];
    float s = 0.f, q = 0.f;
    for (int v = node0; v < node1; ++v) {
        int gb = batch[v];
        if (gb != gcur) {
            atomicAdd(&sums[gcur * CD + c], s);
            atomicAdd(&sumsq[gcur * CD + c], q);
            s = 0.f; q = 0.f; gcur = gb;
        }
        float xv = x[(size_t)v * CD + c];
        float val = 0.5f * xv * (1.f + erff(xv * 0.70710678118654752f));
        um[(size_t)v * CD + c] = f2h(val);
        s += val; q += val * val;
    }
    atomicAdd(&sums[gcur * CD + c], s);
    atomicAdd(&sumsq[gcur * CD + c], q);
}

__global__ void gn_finalize_kernel(const float* __restrict__ sums,
                                   const float* __restrict__ sumsq,
                                   const int* __restrict__ cntg,
                                   const float* __restrict__ w,
                                   const float* __restrict__ ms,
                                   float* __restrict__ scaleA,
                                   float* __restrict__ shiftB) {
    int i = blockIdx.x * blockDim.x + threadIdx.x;
    if (i >= GG * CD) return;
    int g = i / CD, c = i % CD;
    float cnt  = fmaxf((float)cntg[g], 1.0f);
    float mean = sums[i] / cnt;
    float ex2  = sumsq[i] / cnt;
    float msm  = ms[c] * mean;
    float var  = ex2 - 2.f * msm * mean + msm * msm;
    scaleA[i] = w[c] * rsqrtf(var + EPSV);
    shiftB[i] = msm;
}

// MODE 0: first (no residual): h=val, g=val, g_h=f2h(val)
// MODE 1: mid (residual):      h+=val (write), g=val.. actually val+=h
// MODE 2: final (residual):    write only h_h = f2h(val + h)
template<int MODE>
__global__ void gn_apply_kernel(const u16* __restrict__ x,
                                const int* __restrict__ batch,
                                const float* __restrict__ scaleA,
                                const float* __restrict__ shiftB,
                                const float* __restrict__ bvec,
                                float* __restrict__ h,
                                float* __restrict__ g,
                                u16* __restrict__ g_h,
                                u16* __restrict__ h_h) {
    int i = blockIdx.x * blockDim.x + threadIdx.x;   // over NN*64
    if (i >= NN * (CD / 4)) return;
    int v = i >> 6, c4 = (i & 63) << 2;
    int gb = batch[v];
    size_t idx = (size_t)v * CD + c4;
    ushort4 xv = *(const ushort4*)&x[idx];
    float4 sA = *(const float4*)&scaleA[gb * CD + c4];
    float4 sB = *(const float4*)&shiftB[gb * CD + c4];
    float4 bb = *(const float4*)&bvec[c4];
    float4 val;
    val.x = (h2f(xv.x) - sB.x) * sA.x + bb.x;
    val.y = (h2f(xv.y) - sB.y) * sA.y + bb.y;
    val.z = (h2f(xv.z) - sB.z) * sA.z + bb.z;
    val.w = (h2f(xv.w) - sB.w) * sA.w + bb.w;
    if (MODE >= 1) {
        float4 hv = *(const float4*)&h[idx];
        val.x += hv.x; val.y += hv.y; val.z += hv.z; val.w += hv.w;
    }
    if (MODE == 2) {
        ushort4 ov; ov.x = f2h(val.x); ov.y = f2h(val.y); ov.z = f2h(val.z); ov.w = f2h(val.w);
        *(ushort4*)&h_h[idx] = ov;
        return;
    }
    *(float4*)&h[idx] = val;
    *(float4*)&g[idx] = val;
    ushort4 ov; ov.x = f2h(val.x); ov.y = f2h(val.y); ov.z = f2h(val.z); ov.w = f2h(val.w);
    *(ushort4*)&g_h[idx] = ov;
}

// ---------------------------------------------------------------------------
// GRU elementwise (f16 gate inputs); updates g f32 + g_h f16
// ---------------------------------------------------------------------------
__global__ void gru_kernel(const u16* __restrict__ gi, const u16* __restrict__ gh,
                           float* __restrict__ g, u16* __restrict__ g_h,
                           int rows, int r0) {
    int i = blockIdx.x * blockDim.x + threadIdx.x;   // over rows*64
    if (i >= rows * (CD / 4)) return;
    int rr = i >> 6, c4 = (i & 63) << 2;
    const u16* gip = gi + (size_t)rr * 3 * CD + c4;
    const u16* ghp = gh + (size_t)rr * 3 * CD + c4;
    ushort4 ir = *(const ushort4*)gip;
    ushort4 iz = *(const ushort4*)(gip + CD);
    ushort4 in_ = *(const ushort4*)(gip + 2 * CD);
    ushort4 hr = *(const ushort4*)ghp;
    ushort4 hz = *(const ushort4*)(ghp + CD);
    ushort4 hn = *(const ushort4*)(ghp + 2 * CD);
    size_t gidx = (size_t)(r0 + rr) * CD + c4;
    float4 hold = *(const float4*)&g[gidx];
    float4 outv; ushort4 ob;
    #pragma unroll
    for (int t = 0; t < 4; ++t) {
        float irt = h2f((&ir.x)[t]), izt = h2f((&iz.x)[t]), int_ = h2f((&in_.x)[t]);
        float hrt = h2f((&hr.x)[t]), hzt = h2f((&hz.x)[t]), hnt = h2f((&hn.x)[t]);
        float r = 1.f / (1.f + expf(-(irt + hrt)));
        float z = 1.f / (1.f + expf(-(izt + hzt)));
        float nval = tanhf(int_ + r * hnt);
        float res = (1.f - z) * nval + z * (&hold.x)[t];
        (&outv.x)[t] = res;
        (&ob.x)[t] = f2h(res);
    }
    *(float4*)&g[gidx] = outv;
    *(ushort4*)&g_h[gidx] = ob;
}

// ---------------------------------------------------------------------------
// Host
// ---------------------------------------------------------------------------
extern "C" void kernel_launch(void* const* d_in, const int* in_sizes, int n_in,
                              void* d_out, int out_size, void* d_ws, size_t ws_size,
                              hipStream_t stream) {
    const float* x      = (const float*)d_in[0];
    const int*   ei     = (const int*)d_in[1];
    const int*   batch  = (const int*)d_in[2];
    const float* gcn_w  = (const float*)d_in[3];
    const float* gcn_b  = (const float*)d_in[4];
    const float* gn0_w  = (const float*)d_in[5];
    const float* gn0_b  = (const float*)d_in[6];
    const float* gn0_ms = (const float*)d_in[7];
    const float* ggc_w  = (const float*)d_in[8];
    const float* gru_wih = (const float*)d_in[9];
    const float* gru_whh = (const float*)d_in[10];
    const float* gru_bih = (const float*)d_in[11];
    const float* gru_bhh = (const float*)d_in[12];
    const float* gn_w   = (const float*)d_in[13];
    const float* gn_b   = (const float*)d_in[14];
    const float* gn_ms  = (const float*)d_in[15];
    const float* lin_w  = (const float*)d_in[16];
    const float* lin_b  = (const float*)d_in[17];
    float* outp = (float*)d_out;

    const int* srcv = ei;
    const int* dstv = ei + EE;

    char* base = (char*)d_ws;
    size_t off = 0;
    auto alloc = [&](size_t bytes) -> void* {
        void* p = base + off;
        off = (off + bytes + 255) & ~(size_t)255;
        return p;
    };

    int*   counts  = (int*)alloc(NN * 4);
    int*   cursor  = (int*)alloc(NN * 4);
    int*   cntg    = (int*)alloc(GG * 4);
    size_t zero_end = off;
    int*   offsets = (int*)alloc((NN + 1) * 4);
    int*   srcs    = (int*)alloc((size_t)EE * 4);
    float* wts     = (float*)alloc((size_t)EE * 4);
    float* dinv    = (float*)alloc(NN * 4);
    float* sums    = (float*)alloc(GG * CD * 4);
    float* sumsq   = (float*)alloc(GG * CD * 4);
    float* scaleA  = (float*)alloc(GG * CD * 4);
    float* shiftB  = (float*)alloc(GG * CD * 4);
    // f16 weights
    u16* gcn_wt = (u16*)alloc((size_t)CD * IND * 2);           // [256,128]
    u16* ggc_h  = (u16*)alloc((size_t)6 * CD * CD * 2);        // plain [k][j]
    u16* wih_h  = (u16*)alloc((size_t)LL * 3 * CD * CD * 2);
    u16* whh_h  = (u16*)alloc((size_t)LL * 3 * CD * CD * 2);
    u16* lin_wt = (u16*)alloc((size_t)OUTD * CD * 2);
    u16* Bc     = (u16*)alloc((size_t)6 * 3 * CD * CD * 2);    // combined W@wih^T, [768,256] each
    // activations
    u16*   x_h   = (u16*)alloc((size_t)NN * IND * 2);
    u16*   ax_h  = (u16*)alloc((size_t)NN * IND * 2);
    float* g     = (float*)alloc((size_t)NN * CD * 4);
    u16*   g_h   = (u16*)alloc((size_t)NN * CD * 2);
    float* h     = (float*)alloc((size_t)NN * CD * 4);
    u16*   m_h   = (u16*)alloc((size_t)NN * CD * 2);
    u16*   a_h   = (u16*)alloc((size_t)NN * CD * 2);

    size_t rem = (ws_size > off + 512) ? (ws_size - off - 512) : 0;
    size_t per_row = (size_t)2 * 3 * CD * 2;   // gi + gh per row, f16
    int CH = (int)(rem / per_row);
    if (CH > NN) CH = NN;
    if (CH < 256) CH = 256;
    u16* gi = (u16*)alloc((size_t)CH * 3 * CD * 2);
    u16* gh = (u16*)alloc((size_t)CH * 3 * CD * 2);

    // ---- CSR build + per-graph counts ----
    hipMemsetAsync(counts, 0, zero_end, stream);
    hist_edges_kernel<<<(EE + 255) / 256, 256, 0, stream>>>(dstv, counts);
    hist_batch_kernel<<<64, 256, 0, stream>>>(batch, cntg);
    scan_kernel<<<1, 1024, 0, stream>>>(counts, offsets, dinv);
    fill_kernel<<<(EE + 255) / 256, 256, 0, stream>>>(srcv, dstv, offsets, cursor, dinv, srcs, wts);

    // ---- weight + input conversions ----
    f2h_kernel<<<(NN * IND / 4 + 255) / 256, 256, 0, stream>>>(x, x_h, NN * IND / 4);
    f2h_kernel<<<(CD * IND / 4 + 255) / 256, 256, 0, stream>>>(gcn_w, gcn_wt, CD * IND / 4);
    f2h_kernel<<<(6 * CD * CD / 4 + 255) / 256, 256, 0, stream>>>(ggc_w, ggc_h, 6 * CD * CD / 4);
    f2h_kernel<<<(LL * 3 * CD * CD / 4 + 255) / 256, 256, 0, stream>>>(gru_wih, wih_h, LL * 3 * CD * CD / 4);
    f2h_kernel<<<(LL * 3 * CD * CD / 4 + 255) / 256, 256, 0, stream>>>(gru_whh, whh_h, LL * 3 * CD * CD / 4);
    f2h_kernel<<<(OUTD * CD / 4 + 255) / 256, 256, 0, stream>>>(lin_w, lin_wt, OUTD * CD / 4);

    // ---- Bc[l,i] = wih_l @ ggc[l,i]^T : [768,256], Bc[n,k] = sum_j wih[n,j]*ggc[k,j]
    for (int l = 0; l < LL; ++l)
        for (int i = 0; i < 2; ++i)
            gemm_mfma<false, true><<<dim3(6, 2), 256, 0, stream>>>(
                wih_h + (size_t)l * 3 * CD * CD,
                ggc_h + ((size_t)l * 2 + i) * CD * CD,
                nullptr, nullptr, Bc + ((size_t)l * 2 + i) * 3 * CD * CD,
                3 * CD, CD, CD);

    const int gmx = (NN + 127) / 128;      // 157
    const int nb_gn = (NN + 63) / 64;      // 313
    const int nv4 = (NN * (CD / 4) + 255) / 256;

    // ---- GCNConv: aggregate x (128ch) first, then GEMM ----
    agg_kernel<IND, true><<<NN, 256, 0, stream>>>(x_h, offsets, srcs, wts, dinv, ax_h);
    gemm_mfma<true, true><<<dim3(gmx, CD / 128), 256, 0, stream>>>(ax_h, gcn_wt, gcn_b, nullptr, a_h, NN, CD, IND);

    hipMemsetAsync(sums, 0, 2 * GG * CD * 4, stream);
    gn_partial_kernel<<<nb_gn, 256, 0, stream>>>(a_h, batch, sums, sumsq);
    gn_finalize_kernel<<<(GG * CD + 255) / 256, 256, 0, stream>>>(sums, sumsq, cntg, gn0_w, gn0_ms, scaleA, shiftB);
    gn_apply_kernel<0><<<nv4, 256, 0, stream>>>(a_h, batch, scaleA, shiftB, gn0_b, h, g, g_h, nullptr);

    // ---- gated blocks ----
    for (int l = 0; l < LL; ++l) {
        const u16* whh = whh_h + (size_t)l * 3 * CD * CD;
        const float* bih = gru_bih + (size_t)l * 3 * CD;
        const float* bhh = gru_bhh + (size_t)l * 3 * CD;
        for (int i = 0; i < 2; ++i) {
            const u16* Bci = Bc + ((size_t)l * 2 + i) * 3 * CD * CD;
            // ag = agg(g)  (plain sum over in-edges)
            agg_kernel<CD, false><<<NN, 256, 0, stream>>>(g_h, offsets, srcs, wts, dinv, a_h);
            for (int r0 = 0; r0 < NN; r0 += CH) {
                int rows = NN - r0; if (rows > CH) rows = CH;
                dim3 gg2((rows + 127) / 128, 3 * CD / 128);
                gemm_mfma<true, true><<<gg2, 256, 0, stream>>>(a_h + (size_t)r0 * CD, Bci, bih, nullptr, gi, rows, 3 * CD, CD);
                gemm_mfma<true, true><<<gg2, 256, 0, stream>>>(g_h + (size_t)r0 * CD, whh, bhh, nullptr, gh, rows, 3 * CD, CD);
                gru_kernel<<<(rows * (CD / 4) + 255) / 256, 256, 0, stream>>>(gi, gh, g, g_h, rows, r0);
            }
        }
        hipMemsetAsync(sums, 0, 2 * GG * CD * 4, stream);
        gelu_gn_partial_kernel<<<nb_gn, 256, 0, stream>>>(g, batch, m_h, sums, sumsq);
        gn_finalize_kernel<<<(GG * CD + 255) / 256, 256, 0, stream>>>(sums, sumsq, cntg, gn_w + l * CD, gn_ms + l * CD, scaleA, shiftB);
        if (l < LL - 1)
            gn_apply_kernel<1><<<nv4, 256, 0, stream>>>(m_h, batch, scaleA, shiftB, gn_b + l * CD, h, g, g_h, nullptr);
        else
            gn_apply_kernel<2><<<nv4, 256, 0, stream>>>(m_h, batch, scaleA, shiftB, gn_b + l * CD, h, g, g_h, a_h);
    }

    // ---- final linear on f16 h ----
    gemm_mfma<true, false><<<dim3(gmx, OUTD / 128), 256, 0, stream>>>(a_h, lin_wt, lin_b, outp, nullptr, NN, OUTD, CD);
}

// Round 5
// 873.925 us; speedup vs baseline: 3.1979x; 1.1713x over previous
//
#include <hip/hip_runtime.h>
#include <math.h>

typedef unsigned short u16;
typedef _Float16 f16;
typedef __attribute__((ext_vector_type(8))) _Float16 f16x8;
typedef __attribute__((ext_vector_type(4))) float f32x4;
typedef __attribute__((ext_vector_type(8))) unsigned short u16x8;

constexpr int NN   = 20000;
constexpr int EE   = 320000;
constexpr int CD   = 256;
constexpr int IND  = 128;
constexpr int OUTD = 128;
constexpr int LL   = 3;
constexpr int GG   = 16;
constexpr float EPSV = 1e-5f;

__device__ __forceinline__ u16 f2h(float f) {
    union { f16 h; u16 u; } v; v.h = (f16)f; return v.u;
}
__device__ __forceinline__ float h2f(u16 u) {
    union { u16 u; f16 h; } v; v.u = u; return (float)v.h;
}

// ---------------------------------------------------------------------------
// CSR build
// ---------------------------------------------------------------------------
__global__ void hist_edges_kernel(const int* __restrict__ dst, int* __restrict__ counts) {
    int e = blockIdx.x * blockDim.x + threadIdx.x;
    if (e < EE) atomicAdd(&counts[dst[e]], 1);
}

__global__ void hist_batch_kernel(const int* __restrict__ batch, int* __restrict__ cntg) {
    __shared__ int loc[GG];
    if (threadIdx.x < GG) loc[threadIdx.x] = 0;
    __syncthreads();
    for (int i = blockIdx.x * blockDim.x + threadIdx.x; i < NN; i += gridDim.x * blockDim.x)
        atomicAdd(&loc[batch[i]], 1);
    __syncthreads();
    if (threadIdx.x < GG) atomicAdd(&cntg[threadIdx.x], loc[threadIdx.x]);
}

__global__ __launch_bounds__(1024) void scan_kernel(const int* __restrict__ counts,
                                                    int* __restrict__ offsets,
                                                    float* __restrict__ dinv) {
    __shared__ int ls[1024];
    int t = threadIdx.x;
    const int CHK = (NN + 1023) / 1024;
    int begin = t * CHK;
    int end   = begin + CHK; if (end > NN) end = NN;
    int s = 0;
    for (int i = begin; i < end && i < NN; ++i) s += counts[i];
    ls[t] = s;
    __syncthreads();
    for (int off = 1; off < 1024; off <<= 1) {
        int v = (t >= off) ? ls[t - off] : 0;
        __syncthreads();
        ls[t] += v;
        __syncthreads();
    }
    int run = ls[t] - s;
    for (int i = begin; i < end && i < NN; ++i) {
        offsets[i] = run;
        int c = counts[i];
        run += c;
        dinv[i] = rsqrtf((float)(c + 1));
    }
    if (t == 1023) offsets[NN] = run;
}

__global__ void fill_kernel(const int* __restrict__ src, const int* __restrict__ dst,
                            const int* __restrict__ offsets, int* __restrict__ cursor,
                            const float* __restrict__ dinv,
                            int* __restrict__ srcs, float* __restrict__ wts) {
    int e = blockIdx.x * blockDim.x + threadIdx.x;
    if (e >= EE) return;
    int d = dst[e];
    int p = atomicAdd(&cursor[d], 1);
    int pos = offsets[d] + p;
    int s = src[e];
    srcs[pos] = s;
    wts[pos]  = dinv[s];
}

// ---------------------------------------------------------------------------
// Fused f32 -> f16 conversion of x + all weights (one launch)
// ---------------------------------------------------------------------------
__global__ void conv_all_kernel(const float* __restrict__ x,   const float* __restrict__ gcn_w,
                                const float* __restrict__ ggc, const float* __restrict__ wih,
                                const float* __restrict__ whh, const float* __restrict__ lin,
                                u16* __restrict__ x_h,  u16* __restrict__ gcn_h,
                                u16* __restrict__ ggc_h, u16* __restrict__ wih_h,
                                u16* __restrict__ whh_h, u16* __restrict__ lin_h) {
    const int b0 = NN * IND / 4;
    const int b1 = b0 + CD * IND / 4;
    const int b2 = b1 + 6 * CD * CD / 4;
    const int b3 = b2 + LL * 3 * CD * CD / 4;
    const int b4 = b3 + LL * 3 * CD * CD / 4;
    const int b5 = b4 + OUTD * CD / 4;
    int i = blockIdx.x * blockDim.x + threadIdx.x;
    if (i >= b5) return;
    const float* src; u16* dst; int base;
    if (i < b0)      { src = x;     dst = x_h;   base = 0;  }
    else if (i < b1) { src = gcn_w; dst = gcn_h; base = b0; }
    else if (i < b2) { src = ggc;   dst = ggc_h; base = b1; }
    else if (i < b3) { src = wih;   dst = wih_h; base = b2; }
    else if (i < b4) { src = whh;   dst = whh_h; base = b3; }
    else             { src = lin;   dst = lin_h; base = b4; }
    int j = i - base;
    float4 v = ((const float4*)src)[j];
    ushort4 o;
    o.x = f2h(v.x); o.y = f2h(v.y); o.z = f2h(v.z); o.w = f2h(v.w);
    ((ushort4*)dst)[j] = o;
}

// ---------------------------------------------------------------------------
// f16 MFMA GEMM tile body: C[M,N] = A[M,K] * B^T (B stored [N,K]) (+bias)
// 128x128 tile, BK=64, 4 waves (2x2 of 64x64), global_load_lds width 16.
// ---------------------------------------------------------------------------
template<bool BIAS, bool OUTH>
__device__ __forceinline__ void gemm_tile(const u16* __restrict__ A,
                                          const u16* __restrict__ B,
                                          const float* __restrict__ bias,
                                          float* __restrict__ Cf,
                                          u16* __restrict__ Ch,
                                          int M, int N, int K,
                                          int bm, int bn,
                                          u16* As, u16* Bs) {
    const int tid  = threadIdx.x;
    const int lane = tid & 63;
    const int wave = tid >> 6;
    const int wr = wave >> 1, wc = wave & 1;

    f32x4 acc[4][4];
    #pragma unroll
    for (int i = 0; i < 4; ++i)
        #pragma unroll
        for (int j = 0; j < 4; ++j) acc[i][j] = (f32x4)0.f;

    const int srow = tid >> 3;        // 0..31
    const int skc  = (tid & 7) * 8;   // k element offset

    const int fr = lane & 15;
    const int kg = (lane >> 4) * 8;

    for (int k0 = 0; k0 < K; k0 += 64) {
        #pragma unroll
        for (int it = 0; it < 4; ++it) {
            int row  = srow + it * 32;
            int arow = bm + row; if (arow >= M) arow = M - 1;
            const u16* ga = &A[(size_t)arow * K + k0 + skc];
            const u16* gb = &B[(size_t)(bn + row) * K + k0 + skc];
            __builtin_amdgcn_global_load_lds(
                (const __attribute__((address_space(1))) void*)ga,
                (__attribute__((address_space(3))) void*)((char*)As + it * 4096 + tid * 16),
                16, 0, 0);
            __builtin_amdgcn_global_load_lds(
                (const __attribute__((address_space(1))) void*)gb,
                (__attribute__((address_space(3))) void*)((char*)Bs + it * 4096 + tid * 16),
                16, 0, 0);
        }
        __syncthreads();

        #pragma unroll
        for (int ks = 0; ks < 2; ++ks) {
            f16x8 af[4], bfr[4];
            #pragma unroll
            for (int m2 = 0; m2 < 4; ++m2)
                af[m2] = *(const f16x8*)&As[(wr * 64 + m2 * 16 + fr) * 64 + ks * 32 + kg];
            #pragma unroll
            for (int n2 = 0; n2 < 4; ++n2)
                bfr[n2] = *(const f16x8*)&Bs[(wc * 64 + n2 * 16 + fr) * 64 + ks * 32 + kg];
            #pragma unroll
            for (int m2 = 0; m2 < 4; ++m2)
                #pragma unroll
                for (int n2 = 0; n2 < 4; ++n2)
                    acc[m2][n2] = __builtin_amdgcn_mfma_f32_16x16x32_f16(af[m2], bfr[n2], acc[m2][n2], 0, 0, 0);
        }
        __syncthreads();
    }

    const int fq = lane >> 4;
    float bv[4];
    if (BIAS) {
        #pragma unroll
        for (int n2 = 0; n2 < 4; ++n2) bv[n2] = bias[bn + wc * 64 + n2 * 16 + fr];
    }
    #pragma unroll
    for (int m2 = 0; m2 < 4; ++m2) {
        int rbase = bm + wr * 64 + m2 * 16 + fq * 4;
        #pragma unroll
        for (int n2 = 0; n2 < 4; ++n2) {
            int col = bn + wc * 64 + n2 * 16 + fr;
            #pragma unroll
            for (int j = 0; j < 4; ++j) {
                int r = rbase + j;
                if (r < M) {
                    float v = acc[m2][n2][j];
                    if (BIAS) v += bv[n2];
                    if (OUTH) Ch[(size_t)r * N + col] = f2h(v);
                    else      Cf[(size_t)r * N + col] = v;
                }
            }
        }
    }
}

template<bool BIAS, bool OUTH>
__global__ __launch_bounds__(256) void gemm_mfma(const u16* __restrict__ A,
                                                 const u16* __restrict__ B,
                                                 const float* __restrict__ bias,
                                                 float* __restrict__ Cf,
                                                 u16* __restrict__ Ch,
                                                 int M, int N, int K) {
    __shared__ u16 As[128 * 64];
    __shared__ u16 Bs[128 * 64];
    gemm_tile<BIAS, OUTH>(A, B, bias, Cf, Ch, M, N, K,
                          blockIdx.x * 128, blockIdx.y * 128, As, Bs);
}

// All 6 Bc = wih_l @ ggc[l,i]^T  (768x256 each) in ONE launch: 72 blocks
__global__ __launch_bounds__(256) void gemm_bc_kernel(const u16* __restrict__ wih_h,
                                                      const u16* __restrict__ ggc_h,
                                                      u16* __restrict__ Bc) {
    __shared__ u16 As[128 * 64];
    __shared__ u16 Bs[128 * 64];
    int b = blockIdx.x;            // 0..71
    int mat = b / 12, rem = b % 12;
    int bx = rem % 6, by = rem / 6;
    gemm_tile<false, true>(wih_h + (size_t)(mat >> 1) * 3 * CD * CD,
                           ggc_h + (size_t)mat * CD * CD,
                           nullptr, nullptr,
                           Bc + (size_t)mat * 3 * CD * CD,
                           3 * CD, CD, CD, bx * 128, by * 128, As, Bs);
}

// ---------------------------------------------------------------------------
// Edge aggregation: 256 thr = NG edge-groups x LPE lanes (16B/lane)
// GCN: out = dinv[v]*sum(wts*feat[src]) + dinv[v]^2*feat[v]; else plain sum.
// ---------------------------------------------------------------------------
template<int CHN, bool GCN>
__global__ __launch_bounds__(256) void agg_kernel(const u16* __restrict__ feat,
                                                  const int* __restrict__ offsets,
                                                  const int* __restrict__ srcs,
                                                  const float* __restrict__ wts,
                                                  const float* __restrict__ dinv,
                                                  u16* __restrict__ outp) {
    constexpr int LPE = CHN / 8;      // lanes per edge (32 for 256ch, 16 for 128ch)
    constexpr int NG  = 256 / LPE;    // concurrent edges (8 / 16)
    __shared__ float red[NG * CHN];
    const int v   = blockIdx.x;
    const int grp = threadIdx.x / LPE;
    const int ln  = threadIdx.x % LPE;
    const int o0 = offsets[v], o1 = offsets[v + 1];
    float a[8];
    #pragma unroll
    for (int t = 0; t < 8; ++t) a[t] = 0.f;
    for (int o = o0 + grp; o < o1; o += NG) {
        int s = srcs[o];
        float w = GCN ? wts[o] : 1.0f;
        u16x8 mv = *(const u16x8*)&feat[(size_t)s * CHN + ln * 8];
        #pragma unroll
        for (int t = 0; t < 8; ++t) a[t] += w * h2f(mv[t]);
    }
    *(float4*)&red[grp * CHN + ln * 8]     = make_float4(a[0], a[1], a[2], a[3]);
    *(float4*)&red[grp * CHN + ln * 8 + 4] = make_float4(a[4], a[5], a[6], a[7]);
    __syncthreads();
    if (threadIdx.x < CHN / 4) {
        int c4 = threadIdx.x * 4;
        float4 tot = *(const float4*)&red[c4];
        #pragma unroll
        for (int q = 1; q < NG; ++q) {
            float4 p = *(const float4*)&red[q * CHN + c4];
            tot.x += p.x; tot.y += p.y; tot.z += p.z; tot.w += p.w;
        }
        if (GCN) {
            float dv = dinv[v];
            ushort4 sv = *(const ushort4*)&feat[(size_t)v * CHN + c4];
            tot.x = dv * tot.x + dv * dv * h2f(sv.x);
            tot.y = dv * tot.y + dv * dv * h2f(sv.y);
            tot.z = dv * tot.z + dv * dv * h2f(sv.z);
            tot.w = dv * tot.w + dv * dv * h2f(sv.w);
        }
        ushort4 ov;
        ov.x = f2h(tot.x); ov.y = f2h(tot.y); ov.z = f2h(tot.z); ov.w = f2h(tot.w);
        *(ushort4*)&outp[(size_t)v * CHN + c4] = ov;
    }
}

// ---------------------------------------------------------------------------
// GraphNorm
// ---------------------------------------------------------------------------
__global__ __launch_bounds__(256) void gn_partial_kernel(const u16* __restrict__ x,
                                                         const int* __restrict__ batch,
                                                         float* __restrict__ sums,
                                                         float* __restrict__ sumsq) {
    int c = threadIdx.x;
    int node0 = blockIdx.x * 64;
    if (node0 >= NN) return;
    int node1 = node0 + 64; if (node1 > NN) node1 = NN;
    int gcur = batch[node0];
    float s = 0.f, q = 0.f;
    for (int v = node0; v < node1; ++v) {
        int gb = batch[v];
        if (gb != gcur) {
            atomicAdd(&sums[gcur * CD + c], s);
            atomicAdd(&sumsq[gcur * CD + c], q);
            s = 0.f; q = 0.f; gcur = gb;
        }
        float val = h2f(x[(size_t)v * CD + c]);
        s += val; q += val * val;
    }
    atomicAdd(&sums[gcur * CD + c], s);
    atomicAdd(&sumsq[gcur * CD + c], q);
}

// gelu(exact) on f16 state, write f16 um + partial sums
__global__ __launch_bounds__(256) void gelu_gn_partial_kernel(const u16* __restrict__ x,
                                                              const int* __restrict__ batch,
                                                              u16* __restrict__ um,
                                                              float* __restrict__ sums,
                                                              float* __restrict__ sumsq) {
    int c = threadIdx.x;
    int node0 = blockIdx.x * 64;
    if (node0 >= NN) return;
    int node1 = node0 + 64; if (node1 > NN) node1 = NN;
    int gcur = batch[node0];
    float s = 0.f, q = 0.f;
    for (int v = node0; v < node1; ++v) {
        int gb = batch[v];
        if (gb != gcur) {
            atomicAdd(&sums[gcur * CD + c], s);
            atomicAdd(&sumsq[gcur * CD + c], q);
            s = 0.f; q = 0.f; gcur = gb;
        }
        float xv = h2f(x[(size_t)v * CD + c]);
        float val = 0.5f * xv * (1.f + erff(xv * 0.70710678118654752f));
        um[(size_t)v * CD + c] = f2h(val);
        s += val; q += val * val;
    }
    atomicAdd(&sums[gcur * CD + c], s);
    atomicAdd(&sumsq[gcur * CD + c], q);
}

__global__ void gn_finalize_kernel(const float* __restrict__ sums,
                                   const float* __restrict__ sumsq,
                                   const int* __restrict__ cntg,
                                   const float* __restrict__ w,
                                   const float* __restrict__ ms,
                                   float* __restrict__ scaleA,
                                   float* __restrict__ shiftB) {
    int i = blockIdx.x * blockDim.x + threadIdx.x;
    if (i >= GG * CD) return;
    int g = i / CD, c = i % CD;
    float cnt  = fmaxf((float)cntg[g], 1.0f);
    float mean = sums[i] / cnt;
    float ex2  = sumsq[i] / cnt;
    float msm  = ms[c] * mean;
    float var  = ex2 - 2.f * msm * mean + msm * msm;
    scaleA[i] = w[c] * rsqrtf(var + EPSV);
    shiftB[i] = msm;
}

// MODE 0: first (no residual): h=val, g_h=f2h(val)
// MODE 1: mid (residual):      val+=h; h=val; g_h=f2h(val)
// MODE 2: final (residual):    write only h_h = f2h(val + h)
template<int MODE>
__global__ void gn_apply_kernel(const u16* __restrict__ x,
                                const int* __restrict__ batch,
                                const float* __restrict__ scaleA,
                                const float* __restrict__ shiftB,
                                const float* __restrict__ bvec,
                                float* __restrict__ h,
                                u16* __restrict__ g_h,
                                u16* __restrict__ h_h) {
    int i = blockIdx.x * blockDim.x + threadIdx.x;   // over NN*64
    if (i >= NN * (CD / 4)) return;
    int v = i >> 6, c4 = (i & 63) << 2;
    int gb = batch[v];
    size_t idx = (size_t)v * CD + c4;
    ushort4 xv = *(const ushort4*)&x[idx];
    float4 sA = *(const float4*)&scaleA[gb * CD + c4];
    float4 sB = *(const float4*)&shiftB[gb * CD + c4];
    float4 bb = *(const float4*)&bvec[c4];
    float4 val;
    val.x = (h2f(xv.x) - sB.x) * sA.x + bb.x;
    val.y = (h2f(xv.y) - sB.y) * sA.y + bb.y;
    val.z = (h2f(xv.z) - sB.z) * sA.z + bb.z;
    val.w = (h2f(xv.w) - sB.w) * sA.w + bb.w;
    if (MODE >= 1) {
        float4 hv = *(const float4*)&h[idx];
        val.x += hv.x; val.y += hv.y; val.z += hv.z; val.w += hv.w;
    }
    ushort4 ov; ov.x = f2h(val.x); ov.y = f2h(val.y); ov.z = f2h(val.z); ov.w = f2h(val.w);
    if (MODE == 2) {
        *(ushort4*)&h_h[idx] = ov;
        return;
    }
    *(float4*)&h[idx] = val;
    *(ushort4*)&g_h[idx] = ov;
}

// ---------------------------------------------------------------------------
// GRU elementwise (f16 gates, f16 state)
// ---------------------------------------------------------------------------
__global__ void gru_kernel(const u16* __restrict__ gi, const u16* __restrict__ gh,
                           u16* __restrict__ g_h, int rows, int r0) {
    int i = blockIdx.x * blockDim.x + threadIdx.x;   // over rows*64
    if (i >= rows * (CD / 4)) return;
    int rr = i >> 6, c4 = (i & 63) << 2;
    const u16* gip = gi + (size_t)rr * 3 * CD + c4;
    const u16* ghp = gh + (size_t)rr * 3 * CD + c4;
    ushort4 ir = *(const ushort4*)gip;
    ushort4 iz = *(const ushort4*)(gip + CD);
    ushort4 in_ = *(const ushort4*)(gip + 2 * CD);
    ushort4 hr = *(const ushort4*)ghp;
    ushort4 hz = *(const ushort4*)(ghp + CD);
    ushort4 hn = *(const ushort4*)(ghp + 2 * CD);
    size_t gidx = (size_t)(r0 + rr) * CD + c4;
    ushort4 hv = *(const ushort4*)&g_h[gidx];
    ushort4 ob;
    #pragma unroll
    for (int t = 0; t < 4; ++t) {
        float irt = h2f((&ir.x)[t]), izt = h2f((&iz.x)[t]), int_ = h2f((&in_.x)[t]);
        float hrt = h2f((&hr.x)[t]), hzt = h2f((&hz.x)[t]), hnt = h2f((&hn.x)[t]);
        float r = 1.f / (1.f + expf(-(irt + hrt)));
        float z = 1.f / (1.f + expf(-(izt + hzt)));
        float nval = tanhf(int_ + r * hnt);
        float res = (1.f - z) * nval + z * h2f((&hv.x)[t]);
        (&ob.x)[t] = f2h(res);
    }
    *(ushort4*)&g_h[gidx] = ob;
}

// ---------------------------------------------------------------------------
// Host
// ---------------------------------------------------------------------------
extern "C" void kernel_launch(void* const* d_in, const int* in_sizes, int n_in,
                              void* d_out, int out_size, void* d_ws, size_t ws_size,
                              hipStream_t stream) {
    const float* x      = (const float*)d_in[0];
    const int*   ei     = (const int*)d_in[1];
    const int*   batch  = (const int*)d_in[2];
    const float* gcn_w  = (const float*)d_in[3];
    const float* gcn_b  = (const float*)d_in[4];
    const float* gn0_w  = (const float*)d_in[5];
    const float* gn0_b  = (const float*)d_in[6];
    const float* gn0_ms = (const float*)d_in[7];
    const float* ggc_w  = (const float*)d_in[8];
    const float* gru_wih = (const float*)d_in[9];
    const float* gru_whh = (const float*)d_in[10];
    const float* gru_bih = (const float*)d_in[11];
    const float* gru_bhh = (const float*)d_in[12];
    const float* gn_w   = (const float*)d_in[13];
    const float* gn_b   = (const float*)d_in[14];
    const float* gn_ms  = (const float*)d_in[15];
    const float* lin_w  = (const float*)d_in[16];
    const float* lin_b  = (const float*)d_in[17];
    float* outp = (float*)d_out;

    const int* srcv = ei;
    const int* dstv = ei + EE;

    char* base = (char*)d_ws;
    size_t off = 0;
    auto alloc = [&](size_t bytes) -> void* {
        void* p = base + off;
        off = (off + bytes + 255) & ~(size_t)255;
        return p;
    };

    int*   counts  = (int*)alloc(NN * 4);
    int*   cursor  = (int*)alloc(NN * 4);
    int*   cntg    = (int*)alloc(GG * 4);
    size_t zero_end = off;
    int*   offsets = (int*)alloc((NN + 1) * 4);
    int*   srcs    = (int*)alloc((size_t)EE * 4);
    float* wts     = (float*)alloc((size_t)EE * 4);
    float* dinv    = (float*)alloc(NN * 4);
    float* sums    = (float*)alloc(GG * CD * 4);
    float* sumsq   = (float*)alloc(GG * CD * 4);
    float* scaleA  = (float*)alloc(GG * CD * 4);
    float* shiftB  = (float*)alloc(GG * CD * 4);
    // f16 weights
    u16* gcn_wt = (u16*)alloc((size_t)CD * IND * 2);
    u16* ggc_h  = (u16*)alloc((size_t)6 * CD * CD * 2);
    u16* wih_h  = (u16*)alloc((size_t)LL * 3 * CD * CD * 2);
    u16* whh_h  = (u16*)alloc((size_t)LL * 3 * CD * CD * 2);
    u16* lin_wt = (u16*)alloc((size_t)OUTD * CD * 2);
    u16* Bc     = (u16*)alloc((size_t)6 * 3 * CD * CD * 2);
    // activations
    u16*   x_h   = (u16*)alloc((size_t)NN * IND * 2);
    u16*   ax_h  = (u16*)alloc((size_t)NN * IND * 2);
    u16*   g_h   = (u16*)alloc((size_t)NN * CD * 2);
    float* h     = (float*)alloc((size_t)NN * CD * 4);
    u16*   m_h   = (u16*)alloc((size_t)NN * CD * 2);
    u16*   a_h   = (u16*)alloc((size_t)NN * CD * 2);

    size_t rem = (ws_size > off + 512) ? (ws_size - off - 512) : 0;
    size_t per_row = (size_t)2 * 3 * CD * 2;   // gi + gh per row, f16
    int CH = (int)(rem / per_row);
    if (CH > NN) CH = NN;
    if (CH < 256) CH = 256;
    u16* gi = (u16*)alloc((size_t)CH * 3 * CD * 2);
    u16* gh = (u16*)alloc((size_t)CH * 3 * CD * 2);

    // ---- CSR build + per-graph counts ----
    hipMemsetAsync(counts, 0, zero_end, stream);
    hist_edges_kernel<<<(EE + 255) / 256, 256, 0, stream>>>(dstv, counts);
    hist_batch_kernel<<<64, 256, 0, stream>>>(batch, cntg);
    scan_kernel<<<1, 1024, 0, stream>>>(counts, offsets, dinv);
    fill_kernel<<<(EE + 255) / 256, 256, 0, stream>>>(srcv, dstv, offsets, cursor, dinv, srcs, wts);

    // ---- fused conversions (x + all weights) ----
    {
        const int tot4 = NN * IND / 4 + CD * IND / 4 + 6 * CD * CD / 4
                       + 2 * (LL * 3 * CD * CD / 4) + OUTD * CD / 4;
        conv_all_kernel<<<(tot4 + 255) / 256, 256, 0, stream>>>(
            x, gcn_w, ggc_w, gru_wih, gru_whh, lin_w,
            x_h, gcn_wt, ggc_h, wih_h, whh_h, lin_wt);
    }

    // ---- all 6 Bc = wih @ ggc^T in one launch ----
    gemm_bc_kernel<<<72, 256, 0, stream>>>(wih_h, ggc_h, Bc);

    const int gmx = (NN + 127) / 128;      // 157
    const int nb_gn = (NN + 63) / 64;      // 313
    const int nv4 = (NN * (CD / 4) + 255) / 256;

    // ---- GCNConv: aggregate x (128ch) first, then GEMM ----
    agg_kernel<IND, true><<<NN, 256, 0, stream>>>(x_h, offsets, srcs, wts, dinv, ax_h);
    gemm_mfma<true, true><<<dim3(gmx, CD / 128), 256, 0, stream>>>(ax_h, gcn_wt, gcn_b, nullptr, a_h, NN, CD, IND);

    hipMemsetAsync(sums, 0, 2 * GG * CD * 4, stream);
    gn_partial_kernel<<<nb_gn, 256, 0, stream>>>(a_h, batch, sums, sumsq);
    gn_finalize_kernel<<<(GG * CD + 255) / 256, 256, 0, stream>>>(sums, sumsq, cntg, gn0_w, gn0_ms, scaleA, shiftB);
    gn_apply_kernel<0><<<nv4, 256, 0, stream>>>(a_h, batch, scaleA, shiftB, gn0_b, h, g_h, nullptr);

    // ---- gated blocks ----
    for (int l = 0; l < LL; ++l) {
        const u16* whh = whh_h + (size_t)l * 3 * CD * CD;
        const float* bih = gru_bih + (size_t)l * 3 * CD;
        const float* bhh = gru_bhh + (size_t)l * 3 * CD;
        for (int i = 0; i < 2; ++i) {
            const u16* Bci = Bc + ((size_t)l * 2 + i) * 3 * CD * CD;
            agg_kernel<CD, false><<<NN, 256, 0, stream>>>(g_h, offsets, srcs, wts, dinv, a_h);
            for (int r0 = 0; r0 < NN; r0 += CH) {
                int rows = NN - r0; if (rows > CH) rows = CH;
                dim3 gg2((rows + 127) / 128, 3 * CD / 128);
                gemm_mfma<true, true><<<gg2, 256, 0, stream>>>(a_h + (size_t)r0 * CD, Bci, bih, nullptr, gi, rows, 3 * CD, CD);
                gemm_mfma<true, true><<<gg2, 256, 0, stream>>>(g_h + (size_t)r0 * CD, whh, bhh, nullptr, gh, rows, 3 * CD, CD);
                gru_kernel<<<(rows * (CD / 4) + 255) / 256, 256, 0, stream>>>(gi, gh, g_h, rows, r0);
            }
        }
        hipMemsetAsync(sums, 0, 2 * GG * CD * 4, stream);
        gelu_gn_partial_kernel<<<nb_gn, 256, 0, stream>>>(g_h, batch, m_h, sums, sumsq);
        gn_finalize_kernel<<<(GG * CD + 255) / 256, 256, 0, stream>>>(sums, sumsq, cntg, gn_w + l * CD, gn_ms + l * CD, scaleA, shiftB);
        if (l < LL - 1)
            gn_apply_kernel<1><<<nv4, 256, 0, stream>>>(m_h, batch, scaleA, shiftB, gn_b + l * CD, h, g_h, nullptr);
        else
            gn_apply_kernel<2><<<nv4, 256, 0, stream>>>(m_h, batch, scaleA, shiftB, gn_b + l * CD, h, g_h, a_h);
    }

    // ---- final linear on f16 h ----
    gemm_mfma<true, false><<<dim3(gmx, OUTD / 128), 256, 0, stream>>>(a_h, lin_wt, lin_b, outp, nullptr, NN, OUTD, CD);
}

// Round 6
// 774.842 us; speedup vs baseline: 3.6069x; 1.1279x over previous
//
#include <hip/hip_runtime.h>
#include <math.h>

typedef unsigned short u16;
typedef _Float16 f16;
typedef __attribute__((ext_vector_type(8))) _Float16 f16x8;
typedef __attribute__((ext_vector_type(4))) float f32x4;
typedef __attribute__((ext_vector_type(8))) unsigned short u16x8;

constexpr int NN   = 20000;
constexpr int EE   = 320000;
constexpr int CD   = 256;
constexpr int IND  = 128;
constexpr int OUTD = 128;
constexpr int LL   = 3;
constexpr int GG   = 16;
constexpr float EPSV = 1e-5f;

__device__ __forceinline__ u16 f2h(float f) {
    union { f16 h; u16 u; } v; v.h = (f16)f; return v.u;
}
__device__ __forceinline__ float h2f(u16 u) {
    union { u16 u; f16 h; } v; v.u = u; return (float)v.h;
}

// ---------------------------------------------------------------------------
// CSR build: fused edge histogram + batch histogram
// ---------------------------------------------------------------------------
__global__ void hist_kernel(const int* __restrict__ dst, const int* __restrict__ batch,
                            int* __restrict__ counts, int* __restrict__ cntg) {
    __shared__ int loc[GG];
    if (threadIdx.x < GG) loc[threadIdx.x] = 0;
    __syncthreads();
    int stride = gridDim.x * blockDim.x;
    for (int e = blockIdx.x * blockDim.x + threadIdx.x; e < EE; e += stride)
        atomicAdd(&counts[dst[e]], 1);
    for (int i = blockIdx.x * blockDim.x + threadIdx.x; i < NN; i += stride)
        atomicAdd(&loc[batch[i]], 1);
    __syncthreads();
    if (threadIdx.x < GG) atomicAdd(&cntg[threadIdx.x], loc[threadIdx.x]);
}

__global__ __launch_bounds__(1024) void scan_kernel(const int* __restrict__ counts,
                                                    int* __restrict__ offsets,
                                                    float* __restrict__ dinv) {
    __shared__ int ls[1024];
    int t = threadIdx.x;
    const int CHK = (NN + 1023) / 1024;
    int begin = t * CHK;
    int end   = begin + CHK; if (end > NN) end = NN;
    int s = 0;
    for (int i = begin; i < end && i < NN; ++i) s += counts[i];
    ls[t] = s;
    __syncthreads();
    for (int off = 1; off < 1024; off <<= 1) {
        int v = (t >= off) ? ls[t - off] : 0;
        __syncthreads();
        ls[t] += v;
        __syncthreads();
    }
    int run = ls[t] - s;
    for (int i = begin; i < end && i < NN; ++i) {
        offsets[i] = run;
        int c = counts[i];
        run += c;
        dinv[i] = rsqrtf((float)(c + 1));
    }
    if (t == 1023) offsets[NN] = run;
}

__global__ void fill_kernel(const int* __restrict__ src, const int* __restrict__ dst,
                            const int* __restrict__ offsets, int* __restrict__ cursor,
                            const float* __restrict__ dinv,
                            int* __restrict__ srcs, float* __restrict__ wts) {
    int e = blockIdx.x * blockDim.x + threadIdx.x;
    if (e >= EE) return;
    int d = dst[e];
    int p = atomicAdd(&cursor[d], 1);
    int pos = offsets[d] + p;
    int s = src[e];
    srcs[pos] = s;
    wts[pos]  = dinv[s];
}

// ---------------------------------------------------------------------------
// Fused f32 -> f16 conversion of x + all weights (one launch)
// ---------------------------------------------------------------------------
__global__ void conv_all_kernel(const float* __restrict__ x,   const float* __restrict__ gcn_w,
                                const float* __restrict__ ggc, const float* __restrict__ wih,
                                const float* __restrict__ whh, const float* __restrict__ lin,
                                u16* __restrict__ x_h,  u16* __restrict__ gcn_h,
                                u16* __restrict__ ggc_h, u16* __restrict__ wih_h,
                                u16* __restrict__ whh_h, u16* __restrict__ lin_h) {
    const int b0 = NN * IND / 4;
    const int b1 = b0 + CD * IND / 4;
    const int b2 = b1 + 6 * CD * CD / 4;
    const int b3 = b2 + LL * 3 * CD * CD / 4;
    const int b4 = b3 + LL * 3 * CD * CD / 4;
    const int b5 = b4 + OUTD * CD / 4;
    int i = blockIdx.x * blockDim.x + threadIdx.x;
    if (i >= b5) return;
    const float* src; u16* dst; int base;
    if (i < b0)      { src = x;     dst = x_h;   base = 0;  }
    else if (i < b1) { src = gcn_w; dst = gcn_h; base = b0; }
    else if (i < b2) { src = ggc;   dst = ggc_h; base = b1; }
    else if (i < b3) { src = wih;   dst = wih_h; base = b2; }
    else if (i < b4) { src = whh;   dst = whh_h; base = b3; }
    else             { src = lin;   dst = lin_h; base = b4; }
    int j = i - base;
    float4 v = ((const float4*)src)[j];
    ushort4 o;
    o.x = f2h(v.x); o.y = f2h(v.y); o.z = f2h(v.z); o.w = f2h(v.w);
    ((ushort4*)dst)[j] = o;
}

// ---------------------------------------------------------------------------
// f16 MFMA GEMM tile body: C[M,N] = A[M,K] * B^T (B stored [N,K]) (+bias)
// 128x128 tile, BK=64, 4 waves (2x2 of 64x64), global_load_lds width 16.
// ---------------------------------------------------------------------------
template<bool BIAS, bool OUTH>
__device__ __forceinline__ void gemm_tile(const u16* __restrict__ A,
                                          const u16* __restrict__ B,
                                          const float* __restrict__ bias,
                                          float* __restrict__ Cf,
                                          u16* __restrict__ Ch,
                                          int M, int N, int K,
                                          int bm, int bn,
                                          u16* As, u16* Bs) {
    const int tid  = threadIdx.x;
    const int lane = tid & 63;
    const int wave = tid >> 6;
    const int wr = wave >> 1, wc = wave & 1;

    f32x4 acc[4][4];
    #pragma unroll
    for (int i = 0; i < 4; ++i)
        #pragma unroll
        for (int j = 0; j < 4; ++j) acc[i][j] = (f32x4)0.f;

    const int srow = tid >> 3;        // 0..31
    const int skc  = (tid & 7) * 8;   // k element offset

    const int fr = lane & 15;
    const int kg = (lane >> 4) * 8;

    for (int k0 = 0; k0 < K; k0 += 64) {
        #pragma unroll
        for (int it = 0; it < 4; ++it) {
            int row  = srow + it * 32;
            int arow = bm + row; if (arow >= M) arow = M - 1;
            const u16* ga = &A[(size_t)arow * K + k0 + skc];
            const u16* gb = &B[(size_t)(bn + row) * K + k0 + skc];
            __builtin_amdgcn_global_load_lds(
                (const __attribute__((address_space(1))) void*)ga,
                (__attribute__((address_space(3))) void*)((char*)As + it * 4096 + tid * 16),
                16, 0, 0);
            __builtin_amdgcn_global_load_lds(
                (const __attribute__((address_space(1))) void*)gb,
                (__attribute__((address_space(3))) void*)((char*)Bs + it * 4096 + tid * 16),
                16, 0, 0);
        }
        __syncthreads();

        #pragma unroll
        for (int ks = 0; ks < 2; ++ks) {
            f16x8 af[4], bfr[4];
            #pragma unroll
            for (int m2 = 0; m2 < 4; ++m2)
                af[m2] = *(const f16x8*)&As[(wr * 64 + m2 * 16 + fr) * 64 + ks * 32 + kg];
            #pragma unroll
            for (int n2 = 0; n2 < 4; ++n2)
                bfr[n2] = *(const f16x8*)&Bs[(wc * 64 + n2 * 16 + fr) * 64 + ks * 32 + kg];
            #pragma unroll
            for (int m2 = 0; m2 < 4; ++m2)
                #pragma unroll
                for (int n2 = 0; n2 < 4; ++n2)
                    acc[m2][n2] = __builtin_amdgcn_mfma_f32_16x16x32_f16(af[m2], bfr[n2], acc[m2][n2], 0, 0, 0);
        }
        __syncthreads();
    }

    const int fq = lane >> 4;
    float bv[4];
    if (BIAS) {
        #pragma unroll
        for (int n2 = 0; n2 < 4; ++n2) bv[n2] = bias[bn + wc * 64 + n2 * 16 + fr];
    }
    #pragma unroll
    for (int m2 = 0; m2 < 4; ++m2) {
        int rbase = bm + wr * 64 + m2 * 16 + fq * 4;
        #pragma unroll
        for (int n2 = 0; n2 < 4; ++n2) {
            int col = bn + wc * 64 + n2 * 16 + fr;
            #pragma unroll
            for (int j = 0; j < 4; ++j) {
                int r = rbase + j;
                if (r < M) {
                    float v = acc[m2][n2][j];
                    if (BIAS) v += bv[n2];
                    if (OUTH) Ch[(size_t)r * N + col] = f2h(v);
                    else      Cf[(size_t)r * N + col] = v;
                }
            }
        }
    }
}

template<bool BIAS, bool OUTH>
__global__ __launch_bounds__(256) void gemm_mfma(const u16* __restrict__ A,
                                                 const u16* __restrict__ B,
                                                 const float* __restrict__ bias,
                                                 float* __restrict__ Cf,
                                                 u16* __restrict__ Ch,
                                                 int M, int N, int K) {
    __shared__ u16 As[128 * 64];
    __shared__ u16 Bs[128 * 64];
    gemm_tile<BIAS, OUTH>(A, B, bias, Cf, Ch, M, N, K,
                          blockIdx.x * 128, blockIdx.y * 128, As, Bs);
}

// gi and gh GEMMs in ONE launch: grid.y 0..5 -> gi cols, 6..11 -> gh cols
__global__ __launch_bounds__(256) void gemm_pair_kernel(const u16* __restrict__ A0,
                                                        const u16* __restrict__ B0,
                                                        const float* __restrict__ bias0,
                                                        u16* __restrict__ C0,
                                                        const u16* __restrict__ A1,
                                                        const u16* __restrict__ B1,
                                                        const float* __restrict__ bias1,
                                                        u16* __restrict__ C1,
                                                        int M) {
    __shared__ u16 As[128 * 64];
    __shared__ u16 Bs[128 * 64];
    int jy = blockIdx.y;
    bool sec = jy >= 6;
    int bn = (sec ? jy - 6 : jy) * 128;
    gemm_tile<true, true>(sec ? A1 : A0, sec ? B1 : B0, sec ? bias1 : bias0,
                          nullptr, sec ? C1 : C0,
                          M, 3 * CD, CD, blockIdx.x * 128, bn, As, Bs);
}

// All 6 Bc = wih_l @ ggc[l,i]^T  (768x256 each) in ONE launch: 72 blocks
__global__ __launch_bounds__(256) void gemm_bc_kernel(const u16* __restrict__ wih_h,
                                                      const u16* __restrict__ ggc_h,
                                                      u16* __restrict__ Bc) {
    __shared__ u16 As[128 * 64];
    __shared__ u16 Bs[128 * 64];
    int b = blockIdx.x;            // 0..71
    int mat = b / 12, rem = b % 12;
    int bx = rem % 6, by = rem / 6;
    gemm_tile<false, true>(wih_h + (size_t)(mat >> 1) * 3 * CD * CD,
                           ggc_h + (size_t)mat * CD * CD,
                           nullptr, nullptr,
                           Bc + (size_t)mat * 3 * CD * CD,
                           3 * CD, CD, CD, bx * 128, by * 128, As, Bs);
}

// ---------------------------------------------------------------------------
// Edge aggregation: 256 thr = NG edge-groups x LPE lanes (16B/lane)
// ---------------------------------------------------------------------------
template<int CHN, bool GCN>
__global__ __launch_bounds__(256) void agg_kernel(const u16* __restrict__ feat,
                                                  const int* __restrict__ offsets,
                                                  const int* __restrict__ srcs,
                                                  const float* __restrict__ wts,
                                                  const float* __restrict__ dinv,
                                                  u16* __restrict__ outp) {
    constexpr int LPE = CHN / 8;
    constexpr int NG  = 256 / LPE;
    __shared__ float red[NG * CHN];
    const int v   = blockIdx.x;
    const int grp = threadIdx.x / LPE;
    const int ln  = threadIdx.x % LPE;
    const int o0 = offsets[v], o1 = offsets[v + 1];
    float a[8];
    #pragma unroll
    for (int t = 0; t < 8; ++t) a[t] = 0.f;
    for (int o = o0 + grp; o < o1; o += NG) {
        int s = srcs[o];
        float w = GCN ? wts[o] : 1.0f;
        u16x8 mv = *(const u16x8*)&feat[(size_t)s * CHN + ln * 8];
        #pragma unroll
        for (int t = 0; t < 8; ++t) a[t] += w * h2f(mv[t]);
    }
    *(float4*)&red[grp * CHN + ln * 8]     = make_float4(a[0], a[1], a[2], a[3]);
    *(float4*)&red[grp * CHN + ln * 8 + 4] = make_float4(a[4], a[5], a[6], a[7]);
    __syncthreads();
    if (threadIdx.x < CHN / 4) {
        int c4 = threadIdx.x * 4;
        float4 tot = *(const float4*)&red[c4];
        #pragma unroll
        for (int q = 1; q < NG; ++q) {
            float4 p = *(const float4*)&red[q * CHN + c4];
            tot.x += p.x; tot.y += p.y; tot.z += p.z; tot.w += p.w;
        }
        if (GCN) {
            float dv = dinv[v];
            ushort4 sv = *(const ushort4*)&feat[(size_t)v * CHN + c4];
            tot.x = dv * tot.x + dv * dv * h2f(sv.x);
            tot.y = dv * tot.y + dv * dv * h2f(sv.y);
            tot.z = dv * tot.z + dv * dv * h2f(sv.z);
            tot.w = dv * tot.w + dv * dv * h2f(sv.w);
        }
        ushort4 ov;
        ov.x = f2h(tot.x); ov.y = f2h(tot.y); ov.z = f2h(tot.z); ov.w = f2h(tot.w);
        *(ushort4*)&outp[(size_t)v * CHN + c4] = ov;
    }
}

// ---------------------------------------------------------------------------
// GraphNorm partial sums (f16 input)
// ---------------------------------------------------------------------------
__global__ __launch_bounds__(256) void gn_partial_kernel(const u16* __restrict__ x,
                                                         const int* __restrict__ batch,
                                                         float* __restrict__ sums,
                                                         float* __restrict__ sumsq) {
    int c = threadIdx.x;
    int node0 = blockIdx.x * 64;
    if (node0 >= NN) return;
    int node1 = node0 + 64; if (node1 > NN) node1 = NN;
    int gcur = batch[node0];
    float s = 0.f, q = 0.f;
    for (int v = node0; v < node1; ++v) {
        int gb = batch[v];
        if (gb != gcur) {
            atomicAdd(&sums[gcur * CD + c], s);
            atomicAdd(&sumsq[gcur * CD + c], q);
            s = 0.f; q = 0.f; gcur = gb;
        }
        float val = h2f(x[(size_t)v * CD + c]);
        s += val; q += val * val;
    }
    atomicAdd(&sums[gcur * CD + c], s);
    atomicAdd(&sumsq[gcur * CD + c], q);
}

// gelu(exact) on f16 state, write f16 um + partial sums
__global__ __launch_bounds__(256) void gelu_gn_partial_kernel(const u16* __restrict__ x,
                                                              const int* __restrict__ batch,
                                                              u16* __restrict__ um,
                                                              float* __restrict__ sums,
                                                              float* __restrict__ sumsq) {
    int c = threadIdx.x;
    int node0 = blockIdx.x * 64;
    if (node0 >= NN) return;
    int node1 = node0 + 64; if (node1 > NN) node1 = NN;
    int gcur = batch[node0];
    float s = 0.f, q = 0.f;
    for (int v = node0; v < node1; ++v) {
        int gb = batch[v];
        if (gb != gcur) {
            atomicAdd(&sums[gcur * CD + c], s);
            atomicAdd(&sumsq[gcur * CD + c], q);
            s = 0.f; q = 0.f; gcur = gb;
        }
        float xv = h2f(x[(size_t)v * CD + c]);
        float val = 0.5f * xv * (1.f + erff(xv * 0.70710678118654752f));
        um[(size_t)v * CD + c] = f2h(val);
        s += val; q += val * val;
    }
    atomicAdd(&sums[gcur * CD + c], s);
    atomicAdd(&sumsq[gcur * CD + c], q);
}

// ---------------------------------------------------------------------------
// GN apply with inline finalize.
// MODE 0: h_h=val, g_h=val.  MODE 1: val+=h_h; h_h=val; g_h=val.
// MODE 2: val+=h_h; h_h=val (no g_h write).
// ---------------------------------------------------------------------------
template<int MODE>
__global__ void gn_apply_kernel(const u16* __restrict__ x,
                                const int* __restrict__ batch,
                                const float* __restrict__ sums,
                                const float* __restrict__ sumsq,
                                const int* __restrict__ cntg,
                                const float* __restrict__ w,
                                const float* __restrict__ ms,
                                const float* __restrict__ bvec,
                                u16* __restrict__ h_h,
                                u16* __restrict__ g_h) {
    int i = blockIdx.x * blockDim.x + threadIdx.x;   // over NN*64
    if (i >= NN * (CD / 4)) return;
    int v = i >> 6, c4 = (i & 63) << 2;
    int gb = batch[v];
    size_t idx = (size_t)v * CD + c4;
    ushort4 xv = *(const ushort4*)&x[idx];
    float4 sm = *(const float4*)&sums[gb * CD + c4];
    float4 sq = *(const float4*)&sumsq[gb * CD + c4];
    float4 wv = *(const float4*)&w[c4];
    float4 mv = *(const float4*)&ms[c4];
    float4 bb = *(const float4*)&bvec[c4];
    float rc = 1.0f / fmaxf((float)cntg[gb], 1.0f);
    float4 val;
    #pragma unroll
    for (int t = 0; t < 4; ++t) {
        float mean = (&sm.x)[t] * rc;
        float ex2  = (&sq.x)[t] * rc;
        float msm  = (&mv.x)[t] * mean;
        float var  = ex2 - 2.f * msm * mean + msm * msm;
        float scale = (&wv.x)[t] * rsqrtf(var + EPSV);
        (&val.x)[t] = (h2f((&xv.x)[t]) - msm) * scale + (&bb.x)[t];
    }
    if (MODE >= 1) {
        ushort4 hv = *(const ushort4*)&h_h[idx];
        val.x += h2f(hv.x); val.y += h2f(hv.y); val.z += h2f(hv.z); val.w += h2f(hv.w);
    }
    ushort4 ov; ov.x = f2h(val.x); ov.y = f2h(val.y); ov.z = f2h(val.z); ov.w = f2h(val.w);
    *(ushort4*)&h_h[idx] = ov;
    if (MODE < 2) *(ushort4*)&g_h[idx] = ov;
}

// ---------------------------------------------------------------------------
// GRU elementwise (f16 gates, f16 state)
// ---------------------------------------------------------------------------
__global__ void gru_kernel(const u16* __restrict__ gi, const u16* __restrict__ gh,
                           u16* __restrict__ g_h, int rows, int r0) {
    int i = blockIdx.x * blockDim.x + threadIdx.x;   // over rows*64
    if (i >= rows * (CD / 4)) return;
    int rr = i >> 6, c4 = (i & 63) << 2;
    const u16* gip = gi + (size_t)rr * 3 * CD + c4;
    const u16* ghp = gh + (size_t)rr * 3 * CD + c4;
    ushort4 ir = *(const ushort4*)gip;
    ushort4 iz = *(const ushort4*)(gip + CD);
    ushort4 in_ = *(const ushort4*)(gip + 2 * CD);
    ushort4 hr = *(const ushort4*)ghp;
    ushort4 hz = *(const ushort4*)(ghp + CD);
    ushort4 hn = *(const ushort4*)(ghp + 2 * CD);
    size_t gidx = (size_t)(r0 + rr) * CD + c4;
    ushort4 hv = *(const ushort4*)&g_h[gidx];
    ushort4 ob;
    #pragma unroll
    for (int t = 0; t < 4; ++t) {
        float irt = h2f((&ir.x)[t]), izt = h2f((&iz.x)[t]), int_ = h2f((&in_.x)[t]);
        float hrt = h2f((&hr.x)[t]), hzt = h2f((&hz.x)[t]), hnt = h2f((&hn.x)[t]);
        float r = 1.f / (1.f + expf(-(irt + hrt)));
        float z = 1.f / (1.f + expf(-(izt + hzt)));
        float nval = tanhf(int_ + r * hnt);
        float res = (1.f - z) * nval + z * h2f((&hv.x)[t]);
        (&ob.x)[t] = f2h(res);
    }
    *(ushort4*)&g_h[gidx] = ob;
}

// ---------------------------------------------------------------------------
// Host
// ---------------------------------------------------------------------------
extern "C" void kernel_launch(void* const* d_in, const int* in_sizes, int n_in,
                              void* d_out, int out_size, void* d_ws, size_t ws_size,
                              hipStream_t stream) {
    const float* x      = (const float*)d_in[0];
    const int*   ei     = (const int*)d_in[1];
    const int*   batch  = (const int*)d_in[2];
    const float* gcn_w  = (const float*)d_in[3];
    const float* gcn_b  = (const float*)d_in[4];
    const float* gn0_w  = (const float*)d_in[5];
    const float* gn0_b  = (const float*)d_in[6];
    const float* gn0_ms = (const float*)d_in[7];
    const float* ggc_w  = (const float*)d_in[8];
    const float* gru_wih = (const float*)d_in[9];
    const float* gru_whh = (const float*)d_in[10];
    const float* gru_bih = (const float*)d_in[11];
    const float* gru_bhh = (const float*)d_in[12];
    const float* gn_w   = (const float*)d_in[13];
    const float* gn_b   = (const float*)d_in[14];
    const float* gn_ms  = (const float*)d_in[15];
    const float* lin_w  = (const float*)d_in[16];
    const float* lin_b  = (const float*)d_in[17];
    float* outp = (float*)d_out;

    const int* srcv = ei;
    const int* dstv = ei + EE;

    char* base = (char*)d_ws;
    size_t off = 0;
    auto alloc = [&](size_t bytes) -> void* {
        void* p = base + off;
        off = (off + bytes + 255) & ~(size_t)255;
        return p;
    };

    // ---- zeroed-at-start region ----
    int*   counts   = (int*)alloc(NN * 4);
    int*   cursor   = (int*)alloc(NN * 4);
    int*   cntg     = (int*)alloc(GG * 4);
    float* sums_all = (float*)alloc((size_t)4 * 2 * GG * CD * 4);  // 4 stages x (sums,sumsq)
    size_t zero_end = off;

    int*   offsets = (int*)alloc((NN + 1) * 4);
    int*   srcs    = (int*)alloc((size_t)EE * 4);
    float* wts     = (float*)alloc((size_t)EE * 4);
    float* dinv    = (float*)alloc(NN * 4);
    // f16 weights
    u16* gcn_wt = (u16*)alloc((size_t)CD * IND * 2);
    u16* ggc_h  = (u16*)alloc((size_t)6 * CD * CD * 2);
    u16* wih_h  = (u16*)alloc((size_t)LL * 3 * CD * CD * 2);
    u16* whh_h  = (u16*)alloc((size_t)LL * 3 * CD * CD * 2);
    u16* lin_wt = (u16*)alloc((size_t)OUTD * CD * 2);
    u16* Bc     = (u16*)alloc((size_t)6 * 3 * CD * CD * 2);
    // activations (all f16)
    u16* x_h  = (u16*)alloc((size_t)NN * IND * 2);
    u16* ax_h = (u16*)alloc((size_t)NN * IND * 2);
    u16* g_h  = (u16*)alloc((size_t)NN * CD * 2);
    u16* h_h  = (u16*)alloc((size_t)NN * CD * 2);
    u16* m_h  = (u16*)alloc((size_t)NN * CD * 2);
    u16* a_h  = (u16*)alloc((size_t)NN * CD * 2);

    size_t rem = (ws_size > off + 512) ? (ws_size - off - 512) : 0;
    size_t per_row = (size_t)2 * 3 * CD * 2;   // gi + gh per row, f16
    int CH = (int)(rem / per_row);
    if (CH > NN) CH = NN;
    if (CH < 256) CH = 256;
    u16* gi = (u16*)alloc((size_t)CH * 3 * CD * 2);
    u16* gh = (u16*)alloc((size_t)CH * 3 * CD * 2);

    // ---- CSR build + per-graph counts ----
    hipMemsetAsync(counts, 0, zero_end, stream);
    hist_kernel<<<512, 256, 0, stream>>>(dstv, batch, counts, cntg);
    scan_kernel<<<1, 1024, 0, stream>>>(counts, offsets, dinv);
    fill_kernel<<<(EE + 255) / 256, 256, 0, stream>>>(srcv, dstv, offsets, cursor, dinv, srcs, wts);

    // ---- fused conversions (x + all weights) ----
    {
        const int tot4 = NN * IND / 4 + CD * IND / 4 + 6 * CD * CD / 4
                       + 2 * (LL * 3 * CD * CD / 4) + OUTD * CD / 4;
        conv_all_kernel<<<(tot4 + 255) / 256, 256, 0, stream>>>(
            x, gcn_w, ggc_w, gru_wih, gru_whh, lin_w,
            x_h, gcn_wt, ggc_h, wih_h, whh_h, lin_wt);
    }

    // ---- all 6 Bc = wih @ ggc^T in one launch ----
    gemm_bc_kernel<<<72, 256, 0, stream>>>(wih_h, ggc_h, Bc);

    const int gmx = (NN + 127) / 128;      // 157
    const int nb_gn = (NN + 63) / 64;      // 313
    const int nv4 = (NN * (CD / 4) + 255) / 256;

    // ---- GCNConv: aggregate x (128ch) first, then GEMM ----
    agg_kernel<IND, true><<<NN, 256, 0, stream>>>(x_h, offsets, srcs, wts, dinv, ax_h);
    gemm_mfma<true, true><<<dim3(gmx, CD / 128), 256, 0, stream>>>(ax_h, gcn_wt, gcn_b, nullptr, a_h, NN, CD, IND);

    {
        float* sums  = sums_all;                 // stage 0
        float* sumsq = sums + GG * CD;
        gn_partial_kernel<<<nb_gn, 256, 0, stream>>>(a_h, batch, sums, sumsq);
        gn_apply_kernel<0><<<nv4, 256, 0, stream>>>(a_h, batch, sums, sumsq, cntg,
                                                    gn0_w, gn0_ms, gn0_b, h_h, g_h);
    }

    // ---- gated blocks ----
    for (int l = 0; l < LL; ++l) {
        const u16* whh = whh_h + (size_t)l * 3 * CD * CD;
        const float* bih = gru_bih + (size_t)l * 3 * CD;
        const float* bhh = gru_bhh + (size_t)l * 3 * CD;
        for (int i = 0; i < 2; ++i) {
            const u16* Bci = Bc + ((size_t)l * 2 + i) * 3 * CD * CD;
            agg_kernel<CD, false><<<NN, 256, 0, stream>>>(g_h, offsets, srcs, wts, dinv, a_h);
            for (int r0 = 0; r0 < NN; r0 += CH) {
                int rows = NN - r0; if (rows > CH) rows = CH;
                gemm_pair_kernel<<<dim3((rows + 127) / 128, 12), 256, 0, stream>>>(
                    a_h + (size_t)r0 * CD, Bci, bih, gi,
                    g_h + (size_t)r0 * CD, whh, bhh, gh, rows);
                gru_kernel<<<(rows * (CD / 4) + 255) / 256, 256, 0, stream>>>(gi, gh, g_h, rows, r0);
            }
        }
        float* sums  = sums_all + (size_t)(1 + l) * 2 * GG * CD;
        float* sumsq = sums + GG * CD;
        gelu_gn_partial_kernel<<<nb_gn, 256, 0, stream>>>(g_h, batch, m_h, sums, sumsq);
        if (l < LL - 1)
            gn_apply_kernel<1><<<nv4, 256, 0, stream>>>(m_h, batch, sums, sumsq, cntg,
                                                        gn_w + l * CD, gn_ms + l * CD, gn_b + l * CD, h_h, g_h);
        else
            gn_apply_kernel<2><<<nv4, 256, 0, stream>>>(m_h, batch, sums, sumsq, cntg,
                                                        gn_w + l * CD, gn_ms + l * CD, gn_b + l * CD, h_h, g_h);
    }

    // ---- final linear on f16 h ----
    gemm_mfma<true, false><<<dim3(gmx, OUTD / 128), 256, 0, stream>>>(h_h, lin_wt, lin_b, outp, nullptr, NN, OUTD, CD);
}

// Round 7
// 739.501 us; speedup vs baseline: 3.7792x; 1.0478x over previous
//
#include <hip/hip_runtime.h>
#include <math.h>

typedef unsigned short u16;
typedef _Float16 f16;
typedef __attribute__((ext_vector_type(8))) _Float16 f16x8;
typedef __attribute__((ext_vector_type(4))) float f32x4;
typedef __attribute__((ext_vector_type(8))) unsigned short u16x8;

constexpr int NN   = 20000;
constexpr int EE   = 320000;
constexpr int CD   = 256;
constexpr int IND  = 128;
constexpr int OUTD = 128;
constexpr int LL   = 3;
constexpr int GG   = 16;
constexpr float EPSV = 1e-5f;

__device__ __forceinline__ u16 f2h(float f) {
    union { f16 h; u16 u; } v; v.h = (f16)f; return v.u;
}
__device__ __forceinline__ float h2f(u16 u) {
    union { u16 u; f16 h; } v; v.u = u; return (float)v.h;
}

// ---------------------------------------------------------------------------
// CSR build: fused edge histogram + batch histogram
// ---------------------------------------------------------------------------
__global__ void hist_kernel(const int* __restrict__ dst, const int* __restrict__ batch,
                            int* __restrict__ counts, int* __restrict__ cntg) {
    __shared__ int loc[GG];
    if (threadIdx.x < GG) loc[threadIdx.x] = 0;
    __syncthreads();
    int stride = gridDim.x * blockDim.x;
    for (int e = blockIdx.x * blockDim.x + threadIdx.x; e < EE; e += stride)
        atomicAdd(&counts[dst[e]], 1);
    for (int i = blockIdx.x * blockDim.x + threadIdx.x; i < NN; i += stride)
        atomicAdd(&loc[batch[i]], 1);
    __syncthreads();
    if (threadIdx.x < GG) atomicAdd(&cntg[threadIdx.x], loc[threadIdx.x]);
}

__global__ __launch_bounds__(1024) void scan_kernel(const int* __restrict__ counts,
                                                    int* __restrict__ offsets,
                                                    float* __restrict__ dinv) {
    __shared__ int ls[1024];
    int t = threadIdx.x;
    const int CHK = (NN + 1023) / 1024;
    int begin = t * CHK;
    int end   = begin + CHK; if (end > NN) end = NN;
    int s = 0;
    for (int i = begin; i < end && i < NN; ++i) s += counts[i];
    ls[t] = s;
    __syncthreads();
    for (int off = 1; off < 1024; off <<= 1) {
        int v = (t >= off) ? ls[t - off] : 0;
        __syncthreads();
        ls[t] += v;
        __syncthreads();
    }
    int run = ls[t] - s;
    for (int i = begin; i < end && i < NN; ++i) {
        offsets[i] = run;
        int c = counts[i];
        run += c;
        dinv[i] = rsqrtf((float)(c + 1));
    }
    if (t == 1023) offsets[NN] = run;
}

__global__ void fill_kernel(const int* __restrict__ src, const int* __restrict__ dst,
                            const int* __restrict__ offsets, int* __restrict__ cursor,
                            const float* __restrict__ dinv,
                            int* __restrict__ srcs, float* __restrict__ wts) {
    int e = blockIdx.x * blockDim.x + threadIdx.x;
    if (e >= EE) return;
    int d = dst[e];
    int p = atomicAdd(&cursor[d], 1);
    int pos = offsets[d] + p;
    int s = src[e];
    srcs[pos] = s;
    wts[pos]  = dinv[s];
}

// ---------------------------------------------------------------------------
// Fused f32 -> f16 conversion of x + all weights (one launch)
// ---------------------------------------------------------------------------
__global__ void conv_all_kernel(const float* __restrict__ x,   const float* __restrict__ gcn_w,
                                const float* __restrict__ ggc, const float* __restrict__ wih,
                                const float* __restrict__ whh, const float* __restrict__ lin,
                                u16* __restrict__ x_h,  u16* __restrict__ gcn_h,
                                u16* __restrict__ ggc_h, u16* __restrict__ wih_h,
                                u16* __restrict__ whh_h, u16* __restrict__ lin_h) {
    const int b0 = NN * IND / 4;
    const int b1 = b0 + CD * IND / 4;
    const int b2 = b1 + 6 * CD * CD / 4;
    const int b3 = b2 + LL * 3 * CD * CD / 4;
    const int b4 = b3 + LL * 3 * CD * CD / 4;
    const int b5 = b4 + OUTD * CD / 4;
    int i = blockIdx.x * blockDim.x + threadIdx.x;
    if (i >= b5) return;
    const float* src; u16* dst; int base;
    if (i < b0)      { src = x;     dst = x_h;   base = 0;  }
    else if (i < b1) { src = gcn_w; dst = gcn_h; base = b0; }
    else if (i < b2) { src = ggc;   dst = ggc_h; base = b1; }
    else if (i < b3) { src = wih;   dst = wih_h; base = b2; }
    else if (i < b4) { src = whh;   dst = whh_h; base = b3; }
    else             { src = lin;   dst = lin_h; base = b4; }
    int j = i - base;
    float4 v = ((const float4*)src)[j];
    ushort4 o;
    o.x = f2h(v.x); o.y = f2h(v.y); o.z = f2h(v.z); o.w = f2h(v.w);
    ((ushort4*)dst)[j] = o;
}

// ---------------------------------------------------------------------------
// f16 MFMA GEMM tile body: C[M,N] = A[M,K] * B^T (B stored [N,K]) (+bias)
// 128x128 tile, BK=64, 4 waves (2x2 of 64x64), global_load_lds width 16.
// LDS XOR-swizzle (T2, rule #21): linear LDS dest + inverse-swizzled global
// source + swizzled ds_read address.  Row stride 128B would otherwise put all
// 16 fr-lanes in the same bank slot (16-way conflict, 5.8M cycles measured).
// ---------------------------------------------------------------------------
template<bool BIAS, bool OUTH>
__device__ __forceinline__ void gemm_tile(const u16* __restrict__ A,
                                          const u16* __restrict__ B,
                                          const float* __restrict__ bias,
                                          float* __restrict__ Cf,
                                          u16* __restrict__ Ch,
                                          int M, int N, int K,
                                          int bm, int bn,
                                          u16* As, u16* Bs) {
    const int tid  = threadIdx.x;
    const int lane = tid & 63;
    const int wave = tid >> 6;
    const int wr = wave >> 1, wc = wave & 1;

    f32x4 acc[4][4];
    #pragma unroll
    for (int i = 0; i < 4; ++i)
        #pragma unroll
        for (int j = 0; j < 4; ++j) acc[i][j] = (f32x4)0.f;

    const int srow = tid >> 3;                              // 0..31
    const int skc  = ((tid & 7) * 8) ^ ((srow & 7) << 3);   // swizzled source k-offset (elems)

    const int fr = lane & 15;
    const int kg = (lane >> 4) * 8;
    const int rsw = (fr & 7) << 3;                          // read-side XOR (elems)

    for (int k0 = 0; k0 < K; k0 += 64) {
        #pragma unroll
        for (int it = 0; it < 4; ++it) {
            int row  = srow + it * 32;
            int arow = bm + row; if (arow >= M) arow = M - 1;
            const u16* ga = &A[(size_t)arow * K + k0 + skc];
            const u16* gb = &B[(size_t)(bn + row) * K + k0 + skc];
            __builtin_amdgcn_global_load_lds(
                (const __attribute__((address_space(1))) void*)ga,
                (__attribute__((address_space(3))) void*)((char*)As + it * 4096 + tid * 16),
                16, 0, 0);
            __builtin_amdgcn_global_load_lds(
                (const __attribute__((address_space(1))) void*)gb,
                (__attribute__((address_space(3))) void*)((char*)Bs + it * 4096 + tid * 16),
                16, 0, 0);
        }
        __syncthreads();

        #pragma unroll
        for (int ks = 0; ks < 2; ++ks) {
            const int col = (ks * 32 + kg) ^ rsw;
            f16x8 af[4], bfr[4];
            #pragma unroll
            for (int m2 = 0; m2 < 4; ++m2)
                af[m2] = *(const f16x8*)&As[(wr * 64 + m2 * 16 + fr) * 64 + col];
            #pragma unroll
            for (int n2 = 0; n2 < 4; ++n2)
                bfr[n2] = *(const f16x8*)&Bs[(wc * 64 + n2 * 16 + fr) * 64 + col];
            #pragma unroll
            for (int m2 = 0; m2 < 4; ++m2)
                #pragma unroll
                for (int n2 = 0; n2 < 4; ++n2)
                    acc[m2][n2] = __builtin_amdgcn_mfma_f32_16x16x32_f16(af[m2], bfr[n2], acc[m2][n2], 0, 0, 0);
        }
        __syncthreads();
    }

    const int fq = lane >> 4;
    float bv[4];
    if (BIAS) {
        #pragma unroll
        for (int n2 = 0; n2 < 4; ++n2) bv[n2] = bias[bn + wc * 64 + n2 * 16 + fr];
    }
    #pragma unroll
    for (int m2 = 0; m2 < 4; ++m2) {
        int rbase = bm + wr * 64 + m2 * 16 + fq * 4;
        #pragma unroll
        for (int n2 = 0; n2 < 4; ++n2) {
            int col = bn + wc * 64 + n2 * 16 + fr;
            #pragma unroll
            for (int j = 0; j < 4; ++j) {
                int r = rbase + j;
                if (r < M) {
                    float v = acc[m2][n2][j];
                    if (BIAS) v += bv[n2];
                    if (OUTH) Ch[(size_t)r * N + col] = f2h(v);
                    else      Cf[(size_t)r * N + col] = v;
                }
            }
        }
    }
}

template<bool BIAS, bool OUTH>
__global__ __launch_bounds__(256) void gemm_mfma(const u16* __restrict__ A,
                                                 const u16* __restrict__ B,
                                                 const float* __restrict__ bias,
                                                 float* __restrict__ Cf,
                                                 u16* __restrict__ Ch,
                                                 int M, int N, int K) {
    __shared__ u16 As[128 * 64];
    __shared__ u16 Bs[128 * 64];
    gemm_tile<BIAS, OUTH>(A, B, bias, Cf, Ch, M, N, K,
                          blockIdx.x * 128, blockIdx.y * 128, As, Bs);
}

// gi and gh GEMMs in ONE 1-D launch with bijective XCD chunk remap (T1/m204):
// within a chunk, the 12 blocks sharing an A-tile are consecutive -> A-tile
// fetched once per XCD L2 instead of ~3x.
__global__ __launch_bounds__(256) void gemm_pair_kernel(const u16* __restrict__ A0,
                                                        const u16* __restrict__ B0,
                                                        const float* __restrict__ bias0,
                                                        u16* __restrict__ C0,
                                                        const u16* __restrict__ A1,
                                                        const u16* __restrict__ B1,
                                                        const float* __restrict__ bias1,
                                                        u16* __restrict__ C1,
                                                        int M) {
    __shared__ u16 As[128 * 64];
    __shared__ u16 Bs[128 * 64];
    const int nwg = gridDim.x;
    const int q = nwg >> 3, r = nwg & 7;
    int xcd = blockIdx.x & 7, idx = blockIdx.x >> 3;
    int nid = (xcd < r ? xcd * (q + 1) : r * (q + 1) + (xcd - r) * q) + idx;
    int a_tile = nid / 12, j = nid % 12;
    bool sec = j >= 6;
    int bn = (sec ? j - 6 : j) * 128;
    gemm_tile<true, true>(sec ? A1 : A0, sec ? B1 : B0, sec ? bias1 : bias0,
                          nullptr, sec ? C1 : C0,
                          M, 3 * CD, CD, a_tile * 128, bn, As, Bs);
}

// All 6 Bc = wih_l @ ggc[l,i]^T  (768x256 each) in ONE launch: 72 blocks
__global__ __launch_bounds__(256) void gemm_bc_kernel(const u16* __restrict__ wih_h,
                                                      const u16* __restrict__ ggc_h,
                                                      u16* __restrict__ Bc) {
    __shared__ u16 As[128 * 64];
    __shared__ u16 Bs[128 * 64];
    int b = blockIdx.x;            // 0..71
    int mat = b / 12, rem = b % 12;
    int bx = rem % 6, by = rem / 6;
    gemm_tile<false, true>(wih_h + (size_t)(mat >> 1) * 3 * CD * CD,
                           ggc_h + (size_t)mat * CD * CD,
                           nullptr, nullptr,
                           Bc + (size_t)mat * 3 * CD * CD,
                           3 * CD, CD, CD, bx * 128, by * 128, As, Bs);
}

// ---------------------------------------------------------------------------
// Edge aggregation: 256 thr = NG edge-groups x LPE lanes (16B/lane)
// ---------------------------------------------------------------------------
template<int CHN, bool GCN>
__global__ __launch_bounds__(256) void agg_kernel(const u16* __restrict__ feat,
                                                  const int* __restrict__ offsets,
                                                  const int* __restrict__ srcs,
                                                  const float* __restrict__ wts,
                                                  const float* __restrict__ dinv,
                                                  u16* __restrict__ outp) {
    constexpr int LPE = CHN / 8;
    constexpr int NG  = 256 / LPE;
    __shared__ float red[NG * CHN];
    const int v   = blockIdx.x;
    const int grp = threadIdx.x / LPE;
    const int ln  = threadIdx.x % LPE;
    const int o0 = offsets[v], o1 = offsets[v + 1];
    float a[8];
    #pragma unroll
    for (int t = 0; t < 8; ++t) a[t] = 0.f;
    for (int o = o0 + grp; o < o1; o += NG) {
        int s = srcs[o];
        float w = GCN ? wts[o] : 1.0f;
        u16x8 mv = *(const u16x8*)&feat[(size_t)s * CHN + ln * 8];
        #pragma unroll
        for (int t = 0; t < 8; ++t) a[t] += w * h2f(mv[t]);
    }
    *(float4*)&red[grp * CHN + ln * 8]     = make_float4(a[0], a[1], a[2], a[3]);
    *(float4*)&red[grp * CHN + ln * 8 + 4] = make_float4(a[4], a[5], a[6], a[7]);
    __syncthreads();
    if (threadIdx.x < CHN / 4) {
        int c4 = threadIdx.x * 4;
        float4 tot = *(const float4*)&red[c4];
        #pragma unroll
        for (int q = 1; q < NG; ++q) {
            float4 p = *(const float4*)&red[q * CHN + c4];
            tot.x += p.x; tot.y += p.y; tot.z += p.z; tot.w += p.w;
        }
        if (GCN) {
            float dv = dinv[v];
            ushort4 sv = *(const ushort4*)&feat[(size_t)v * CHN + c4];
            tot.x = dv * tot.x + dv * dv * h2f(sv.x);
            tot.y = dv * tot.y + dv * dv * h2f(sv.y);
            tot.z = dv * tot.z + dv * dv * h2f(sv.z);
            tot.w = dv * tot.w + dv * dv * h2f(sv.w);
        }
        ushort4 ov;
        ov.x = f2h(tot.x); ov.y = f2h(tot.y); ov.z = f2h(tot.z); ov.w = f2h(tot.w);
        *(ushort4*)&outp[(size_t)v * CHN + c4] = ov;
    }
}

// ---------------------------------------------------------------------------
// GraphNorm partial sums (f16 input)
// ---------------------------------------------------------------------------
__global__ __launch_bounds__(256) void gn_partial_kernel(const u16* __restrict__ x,
                                                         const int* __restrict__ batch,
                                                         float* __restrict__ sums,
                                                         float* __restrict__ sumsq) {
    int c = threadIdx.x;
    int node0 = blockIdx.x * 64;
    if (node0 >= NN) return;
    int node1 = node0 + 64; if (node1 > NN) node1 = NN;
    int gcur = batch[node0];
    float s = 0.f, q = 0.f;
    for (int v = node0; v < node1; ++v) {
        int gb = batch[v];
        if (gb != gcur) {
            atomicAdd(&sums[gcur * CD + c], s);
            atomicAdd(&sumsq[gcur * CD + c], q);
            s = 0.f; q = 0.f; gcur = gb;
        }
        float val = h2f(x[(size_t)v * CD + c]);
        s += val; q += val * val;
    }
    atomicAdd(&sums[gcur * CD + c], s);
    atomicAdd(&sumsq[gcur * CD + c], q);
}

// gelu(exact) on f16 state, write f16 um + partial sums
__global__ __launch_bounds__(256) void gelu_gn_partial_kernel(const u16* __restrict__ x,
                                                              const int* __restrict__ batch,
                                                              u16* __restrict__ um,
                                                              float* __restrict__ sums,
                                                              float* __restrict__ sumsq) {
    int c = threadIdx.x;
    int node0 = blockIdx.x * 64;
    if (node0 >= NN) return;
    int node1 = node0 + 64; if (node1 > NN) node1 = NN;
    int gcur = batch[node0];
    float s = 0.f, q = 0.f;
    for (int v = node0; v < node1; ++v) {
        int gb = batch[v];
        if (gb != gcur) {
            atomicAdd(&sums[gcur * CD + c], s);
            atomicAdd(&sumsq[gcur * CD + c], q);
            s = 0.f; q = 0.f; gcur = gb;
        }
        float xv = h2f(x[(size_t)v * CD + c]);
        float val = 0.5f * xv * (1.f + erff(xv * 0.70710678118654752f));
        um[(size_t)v * CD + c] = f2h(val);
        s += val; q += val * val;
    }
    atomicAdd(&sums[gcur * CD + c], s);
    atomicAdd(&sumsq[gcur * CD + c], q);
}

// ---------------------------------------------------------------------------
// GN apply with inline finalize.
// MODE 0: h_h=val, g_h=val.  MODE 1: val+=h_h; h_h=val; g_h=val.
// MODE 2: val+=h_h; h_h=val (no g_h write).
// ---------------------------------------------------------------------------
template<int MODE>
__global__ void gn_apply_kernel(const u16* __restrict__ x,
                                const int* __restrict__ batch,
                                const float* __restrict__ sums,
                                const float* __restrict__ sumsq,
                                const int* __restrict__ cntg,
                                const float* __restrict__ w,
                                const float* __restrict__ ms,
                                const float* __restrict__ bvec,
                                u16* __restrict__ h_h,
                                u16* __restrict__ g_h) {
    int i = blockIdx.x * blockDim.x + threadIdx.x;   // over NN*64
    if (i >= NN * (CD / 4)) return;
    int v = i >> 6, c4 = (i & 63) << 2;
    int gb = batch[v];
    size_t idx = (size_t)v * CD + c4;
    ushort4 xv = *(const ushort4*)&x[idx];
    float4 sm = *(const float4*)&sums[gb * CD + c4];
    float4 sq = *(const float4*)&sumsq[gb * CD + c4];
    float4 wv = *(const float4*)&w[c4];
    float4 mv = *(const float4*)&ms[c4];
    float4 bb = *(const float4*)&bvec[c4];
    float rc = 1.0f / fmaxf((float)cntg[gb], 1.0f);
    float4 val;
    #pragma unroll
    for (int t = 0; t < 4; ++t) {
        float mean = (&sm.x)[t] * rc;
        float ex2  = (&sq.x)[t] * rc;
        float msm  = (&mv.x)[t] * mean;
        float var  = ex2 - 2.f * msm * mean + msm * msm;
        float scale = (&wv.x)[t] * rsqrtf(var + EPSV);
        (&val.x)[t] = (h2f((&xv.x)[t]) - msm) * scale + (&bb.x)[t];
    }
    if (MODE >= 1) {
        ushort4 hv = *(const ushort4*)&h_h[idx];
        val.x += h2f(hv.x); val.y += h2f(hv.y); val.z += h2f(hv.z); val.w += h2f(hv.w);
    }
    ushort4 ov; ov.x = f2h(val.x); ov.y = f2h(val.y); ov.z = f2h(val.z); ov.w = f2h(val.w);
    *(ushort4*)&h_h[idx] = ov;
    if (MODE < 2) *(ushort4*)&g_h[idx] = ov;
}

// ---------------------------------------------------------------------------
// GRU elementwise (f16 gates, f16 state)
// ---------------------------------------------------------------------------
__global__ void gru_kernel(const u16* __restrict__ gi, const u16* __restrict__ gh,
                           u16* __restrict__ g_h, int rows, int r0) {
    int i = blockIdx.x * blockDim.x + threadIdx.x;   // over rows*64
    if (i >= rows * (CD / 4)) return;
    int rr = i >> 6, c4 = (i & 63) << 2;
    const u16* gip = gi + (size_t)rr * 3 * CD + c4;
    const u16* ghp = gh + (size_t)rr * 3 * CD + c4;
    ushort4 ir = *(const ushort4*)gip;
    ushort4 iz = *(const ushort4*)(gip + CD);
    ushort4 in_ = *(const ushort4*)(gip + 2 * CD);
    ushort4 hr = *(const ushort4*)ghp;
    ushort4 hz = *(const ushort4*)(ghp + CD);
    ushort4 hn = *(const ushort4*)(ghp + 2 * CD);
    size_t gidx = (size_t)(r0 + rr) * CD + c4;
    ushort4 hv = *(const ushort4*)&g_h[gidx];
    ushort4 ob;
    #pragma unroll
    for (int t = 0; t < 4; ++t) {
        float irt = h2f((&ir.x)[t]), izt = h2f((&iz.x)[t]), int_ = h2f((&in_.x)[t]);
        float hrt = h2f((&hr.x)[t]), hzt = h2f((&hz.x)[t]), hnt = h2f((&hn.x)[t]);
        float r = 1.f / (1.f + expf(-(irt + hrt)));
        float z = 1.f / (1.f + expf(-(izt + hzt)));
        float nval = tanhf(int_ + r * hnt);
        float res = (1.f - z) * nval + z * h2f((&hv.x)[t]);
        (&ob.x)[t] = f2h(res);
    }
    *(ushort4*)&g_h[gidx] = ob;
}

// ---------------------------------------------------------------------------
// Host
// ---------------------------------------------------------------------------
extern "C" void kernel_launch(void* const* d_in, const int* in_sizes, int n_in,
                              void* d_out, int out_size, void* d_ws, size_t ws_size,
                              hipStream_t stream) {
    const float* x      = (const float*)d_in[0];
    const int*   ei     = (const int*)d_in[1];
    const int*   batch  = (const int*)d_in[2];
    const float* gcn_w  = (const float*)d_in[3];
    const float* gcn_b  = (const float*)d_in[4];
    const float* gn0_w  = (const float*)d_in[5];
    const float* gn0_b  = (const float*)d_in[6];
    const float* gn0_ms = (const float*)d_in[7];
    const float* ggc_w  = (const float*)d_in[8];
    const float* gru_wih = (const float*)d_in[9];
    const float* gru_whh = (const float*)d_in[10];
    const float* gru_bih = (const float*)d_in[11];
    const float* gru_bhh = (const float*)d_in[12];
    const float* gn_w   = (const float*)d_in[13];
    const float* gn_b   = (const float*)d_in[14];
    const float* gn_ms  = (const float*)d_in[15];
    const float* lin_w  = (const float*)d_in[16];
    const float* lin_b  = (const float*)d_in[17];
    float* outp = (float*)d_out;

    const int* srcv = ei;
    const int* dstv = ei + EE;

    char* base = (char*)d_ws;
    size_t off = 0;
    auto alloc = [&](size_t bytes) -> void* {
        void* p = base + off;
        off = (off + bytes + 255) & ~(size_t)255;
        return p;
    };

    // ---- zeroed-at-start region ----
    int*   counts   = (int*)alloc(NN * 4);
    int*   cursor   = (int*)alloc(NN * 4);
    int*   cntg     = (int*)alloc(GG * 4);
    float* sums_all = (float*)alloc((size_t)4 * 2 * GG * CD * 4);  // 4 stages x (sums,sumsq)
    size_t zero_end = off;

    int*   offsets = (int*)alloc((NN + 1) * 4);
    int*   srcs    = (int*)alloc((size_t)EE * 4);
    float* wts     = (float*)alloc((size_t)EE * 4);
    float* dinv    = (float*)alloc(NN * 4);
    // f16 weights
    u16* gcn_wt = (u16*)alloc((size_t)CD * IND * 2);
    u16* ggc_h  = (u16*)alloc((size_t)6 * CD * CD * 2);
    u16* wih_h  = (u16*)alloc((size_t)LL * 3 * CD * CD * 2);
    u16* whh_h  = (u16*)alloc((size_t)LL * 3 * CD * CD * 2);
    u16* lin_wt = (u16*)alloc((size_t)OUTD * CD * 2);
    u16* Bc     = (u16*)alloc((size_t)6 * 3 * CD * CD * 2);
    // activations (all f16)
    u16* x_h  = (u16*)alloc((size_t)NN * IND * 2);
    u16* ax_h = (u16*)alloc((size_t)NN * IND * 2);
    u16* g_h  = (u16*)alloc((size_t)NN * CD * 2);
    u16* h_h  = (u16*)alloc((size_t)NN * CD * 2);
    u16* m_h  = (u16*)alloc((size_t)NN * CD * 2);
    u16* a_h  = (u16*)alloc((size_t)NN * CD * 2);

    size_t rem = (ws_size > off + 512) ? (ws_size - off - 512) : 0;
    size_t per_row = (size_t)2 * 3 * CD * 2;   // gi + gh per row, f16
    int CH = (int)(rem / per_row);
    if (CH > NN) CH = NN;
    if (CH < 256) CH = 256;
    u16* gi = (u16*)alloc((size_t)CH * 3 * CD * 2);
    u16* gh = (u16*)alloc((size_t)CH * 3 * CD * 2);

    // ---- CSR build + per-graph counts ----
    hipMemsetAsync(counts, 0, zero_end, stream);
    hist_kernel<<<512, 256, 0, stream>>>(dstv, batch, counts, cntg);
    scan_kernel<<<1, 1024, 0, stream>>>(counts, offsets, dinv);
    fill_kernel<<<(EE + 255) / 256, 256, 0, stream>>>(srcv, dstv, offsets, cursor, dinv, srcs, wts);

    // ---- fused conversions (x + all weights) ----
    {
        const int tot4 = NN * IND / 4 + CD * IND / 4 + 6 * CD * CD / 4
                       + 2 * (LL * 3 * CD * CD / 4) + OUTD * CD / 4;
        conv_all_kernel<<<(tot4 + 255) / 256, 256, 0, stream>>>(
            x, gcn_w, ggc_w, gru_wih, gru_whh, lin_w,
            x_h, gcn_wt, ggc_h, wih_h, whh_h, lin_wt);
    }

    // ---- all 6 Bc = wih @ ggc^T in one launch ----
    gemm_bc_kernel<<<72, 256, 0, stream>>>(wih_h, ggc_h, Bc);

    const int gmx = (NN + 127) / 128;      // 157
    const int nb_gn = (NN + 63) / 64;      // 313
    const int nv4 = (NN * (CD / 4) + 255) / 256;

    // ---- GCNConv: aggregate x (128ch) first, then GEMM ----
    agg_kernel<IND, true><<<NN, 256, 0, stream>>>(x_h, offsets, srcs, wts, dinv, ax_h);
    gemm_mfma<true, true><<<dim3(gmx, CD / 128), 256, 0, stream>>>(ax_h, gcn_wt, gcn_b, nullptr, a_h, NN, CD, IND);

    {
        float* sums  = sums_all;                 // stage 0
        float* sumsq = sums + GG * CD;
        gn_partial_kernel<<<nb_gn, 256, 0, stream>>>(a_h, batch, sums, sumsq);
        gn_apply_kernel<0><<<nv4, 256, 0, stream>>>(a_h, batch, sums, sumsq, cntg,
                                                    gn0_w, gn0_ms, gn0_b, h_h, g_h);
    }

    // ---- gated blocks ----
    for (int l = 0; l < LL; ++l) {
        const u16* whh = whh_h + (size_t)l * 3 * CD * CD;
        const float* bih = gru_bih + (size_t)l * 3 * CD;
        const float* bhh = gru_bhh + (size_t)l * 3 * CD;
        for (int i = 0; i < 2; ++i) {
            const u16* Bci = Bc + ((size_t)l * 2 + i) * 3 * CD * CD;
            agg_kernel<CD, false><<<NN, 256, 0, stream>>>(g_h, offsets, srcs, wts, dinv, a_h);
            for (int r0 = 0; r0 < NN; r0 += CH) {
                int rows = NN - r0; if (rows > CH) rows = CH;
                gemm_pair_kernel<<<((rows + 127) / 128) * 12, 256, 0, stream>>>(
                    a_h + (size_t)r0 * CD, Bci, bih, gi,
                    g_h + (size_t)r0 * CD, whh, bhh, gh, rows);
                gru_kernel<<<(rows * (CD / 4) + 255) / 256, 256, 0, stream>>>(gi, gh, g_h, rows, r0);
            }
        }
        float* sums  = sums_all + (size_t)(1 + l) * 2 * GG * CD;
        float* sumsq = sums + GG * CD;
        gelu_gn_partial_kernel<<<nb_gn, 256, 0, stream>>>(g_h, batch, m_h, sums, sumsq);
        if (l < LL - 1)
            gn_apply_kernel<1><<<nv4, 256, 0, stream>>>(m_h, batch, sums, sumsq, cntg,
                                                        gn_w + l * CD, gn_ms + l * CD, gn_b + l * CD, h_h, g_h);
        else
            gn_apply_kernel<2><<<nv4, 256, 0, stream>>>(m_h, batch, sums, sumsq, cntg,
                                                        gn_w + l * CD, gn_ms + l * CD, gn_b + l * CD, h_h, g_h);
    }

    // ---- final linear on f16 h ----
    gemm_mfma<true, false><<<dim3(gmx, OUTD / 128), 256, 0, stream>>>(h_h, lin_wt, lin_b, outp, nullptr, NN, OUTD, CD);
}